// Round 1
// baseline (2102.550 us; speedup 1.0000x reference)
//
#include <hip/hip_runtime.h>
#include <hip/hip_bf16.h>

#define BSZ   32768
#define DD    512
#define EE    16
#define TT    3
#define KTOP  4
#define OO    16

#define BM    32      // samples per block (main kernel)
#define NP    320     // padded GEMM columns (304 real: 256 expert h1 + 48 gate)
#define NCOL  304
#define BKT   16      // K tile

__device__ __forceinline__ float bf2f(unsigned short u) {
  return __uint_as_float(((unsigned int)u) << 16);
}
__device__ __forceinline__ unsigned short f2bf(float f) {
  unsigned int u = __float_as_uint(f);
  u += 0x7fffu + ((u >> 16) & 1u);
  return (unsigned short)(u >> 16);
}

union Smem {
  struct {                     // GEMM phase
    float xs[BKT][BM + 1];     // x tile, transposed [k][m], padded
    float wst[BKT][NP];        // weight tile [k][c]
  } a;
  struct {                     // tail phase
    unsigned short h1s[BM][264];   // h1 as bf16, row padded 256->264
    float lgs[BM][48];             // gating logits [s][t*16+e]
    float W2t[2048];               // [(k*8+j)*16+e]
    float W3t[2048];               // [(j*16+o)*16+e]
    float b2t[128];                // [j*16+e]
    float b3t[256];                // [o*16+e]
    float eoL[16][EE][17];         // expert outputs for a 16-sample half
    float gval[BM][TT][KTOP];
    int   gidx[BM][TT][KTOP];
    float impL[48];
    float loadL[48];
  } b;
};

__global__ __launch_bounds__(256, 2) void k_main(
    const float* __restrict__ x,  const float* __restrict__ wg,
    const float* __restrict__ bg, const float* __restrict__ W1,
    const float* __restrict__ b1, const float* __restrict__ W2,
    const float* __restrict__ b2, const float* __restrict__ W3,
    const float* __restrict__ b3, float* __restrict__ out,
    float* __restrict__ acc_imp, float* __restrict__ acc_load)
{
  __shared__ Smem sm;
  const int tid = threadIdx.x;
  const int b0  = blockIdx.x * BM;
  const int tx  = tid & 15;   // col group: cols tx*20 .. tx*20+19
  const int ty  = tid >> 4;   // row pair: rows ty, ty+16

  float acc[2][20];
#pragma unroll
  for (int i = 0; i < 2; i++)
#pragma unroll
    for (int j = 0; j < 20; j++) acc[i][j] = 0.f;

  const int xrow = tid >> 3;        // 0..31
  const int xk   = (tid & 7) * 2;   // 0,2,...,14

  for (int k0 = 0; k0 < DD; k0 += BKT) {
    __syncthreads();
    // stage x tile (transposed into LDS)
    {
      const float2 v = *reinterpret_cast<const float2*>(
          &x[(size_t)(b0 + xrow) * DD + k0 + xk]);
      sm.a.xs[xk][xrow]     = v.x;
      sm.a.xs[xk + 1][xrow] = v.y;
    }
    // stage W tile: 16 x 320 (expert W1 cols 0..255, gate cols 256..303, pad 0)
#pragma unroll
    for (int rep = 0; rep < 20; rep++) {
      int flat = rep * 256 + tid;
      int kk = flat / NP;
      int c  = flat - kk * NP;
      int k  = k0 + kk;
      float w = 0.f;
      if (c < 256) {
        w = W1[((size_t)(c >> 4) * DD + k) * 16 + (c & 15)];
      } else if (c < NCOL) {
        int cc = c - 256;
        w = wg[((size_t)(cc >> 4) * DD + k) * 16 + (cc & 15)];
      }
      sm.a.wst[kk][c] = w;
    }
    __syncthreads();
#pragma unroll
    for (int kk = 0; kk < BKT; kk++) {
      float xv0 = sm.a.xs[kk][ty];
      float xv1 = sm.a.xs[kk][ty + 16];
      const float* wrow = &sm.a.wst[kk][tx * 20];
#pragma unroll
      for (int j = 0; j < 20; j++) {
        float w = wrow[j];
        acc[0][j] += xv0 * w;
        acc[1][j] += xv1 * w;
      }
    }
  }
  __syncthreads();

  // ---- epilogue: h1 (relu, bf16) and gating logits into LDS ----
#pragma unroll
  for (int i = 0; i < 2; i++) {
    int r = ty + 16 * i;
#pragma unroll
    for (int j = 0; j < 20; j++) {
      int c = tx * 20 + j;
      float v = acc[i][j];
      if (c < 256) {
        sm.b.h1s[r][c] = f2bf(fmaxf(v + b1[c], 0.f));
      } else if (c < NCOL) {
        int cc = c - 256;
        sm.b.lgs[r][cc] = v + bg[cc];
      }
    }
  }
  // tail weights (transposed so lanes with same e broadcast)
  for (int d = tid; d < 2048; d += 256) {
    sm.b.W2t[d] = W2[(d & 15) * 128 + (d >> 4)];
    sm.b.W3t[d] = W3[(d & 15) * 128 + (d >> 4)];
  }
  if (tid < 128) sm.b.b2t[tid] = b2[(tid & 15) * 8 + (tid >> 4)];
  sm.b.b3t[tid] = b3[(tid & 15) * 16 + (tid >> 4)];
  if (tid < 48) { sm.b.impL[tid] = 0.f; sm.b.loadL[tid] = 0.f; }
  __syncthreads();

  // ---- gating: 96 threads = 3 tasks x 32 samples ----
  if (tid < 96) {
    const int t = tid >> 5;
    const int s = tid & 31;
    float v[16];
#pragma unroll
    for (int e = 0; e < 16; e++) v[e] = sm.b.lgs[s][t * 16 + e];
    int idx[5]; float val[5];
#pragma unroll
    for (int p = 0; p < 5; p++) {
      float best = -INFINITY; int bi = 0;
#pragma unroll
      for (int e = 0; e < 16; e++)
        if (v[e] > best) { best = v[e]; bi = e; }
      idx[p] = bi; val[p] = best; v[bi] = -INFINITY;
    }
    if (val[3] - val[4] < 1e-3f) {
      // ambiguous 4th/5th boundary: redo top-4 with f64-accumulated logits
      const float* xr = &x[(size_t)(b0 + s) * DD];
      unsigned used = 0;
      for (int p = 0; p < 4; p++) {
        double best = -1e300; int bi = 0;
        for (int e = 0; e < 16; e++) {
          if ((used >> e) & 1u) continue;
          double a = (double)bg[t * 16 + e];
          for (int d = 0; d < DD; d++)
            a += (double)xr[d] * (double)wg[((size_t)t * DD + d) * 16 + e];
          if (a > best) { best = a; bi = e; }
        }
        used |= 1u << bi; idx[p] = bi; val[p] = (float)best;
      }
    }
    float m = val[0], ex[4], sum = 0.f;
#pragma unroll
    for (int p = 0; p < 4; p++) { ex[p] = expf(val[p] - m); sum += ex[p]; }
#pragma unroll
    for (int p = 0; p < 4; p++) {
      float g = ex[p] / sum;
      sm.b.gval[s][t][p] = g;
      sm.b.gidx[s][t][p] = idx[p];
      atomicAdd(&sm.b.impL[t * 16 + idx[p]], g);
      atomicAdd(&sm.b.loadL[t * 16 + idx[p]], 1.f);
    }
  }
  __syncthreads();

  // ---- expert tail + combine: two halves of 16 samples ----
  const int e  = tid & 15;
  const int s2 = tid >> 4;
  for (int h = 0; h < 2; h++) {
    const int s = h * 16 + s2;
    float h1v[16];
#pragma unroll
    for (int q = 0; q < 4; q++) {
      ushort4 u = *reinterpret_cast<const ushort4*>(&sm.b.h1s[s][e * 16 + q * 4]);
      h1v[q * 4 + 0] = bf2f(u.x);
      h1v[q * 4 + 1] = bf2f(u.y);
      h1v[q * 4 + 2] = bf2f(u.z);
      h1v[q * 4 + 3] = bf2f(u.w);
    }
    float h2v[8];
#pragma unroll
    for (int j = 0; j < 8; j++) {
      float a = sm.b.b2t[j * 16 + e];
#pragma unroll
      for (int k = 0; k < 16; k++) a += h1v[k] * sm.b.W2t[(k * 8 + j) * 16 + e];
      h2v[j] = fmaxf(a, 0.f);
    }
#pragma unroll
    for (int o = 0; o < 16; o++) {
      float a = sm.b.b3t[o * 16 + e];
#pragma unroll
      for (int j = 0; j < 8; j++) a += h2v[j] * sm.b.W3t[(j * 16 + o) * 16 + e];
      sm.b.eoL[s2][e][o] = fmaxf(a, 0.f);
    }
    __syncthreads();
    {
      const int o = e;
      const int b = b0 + s;
#pragma unroll
      for (int t = 0; t < TT; t++) {
        float y = 0.f;
#pragma unroll
        for (int p = 0; p < KTOP; p++)
          y += sm.b.gval[s][t][p] * sm.b.eoL[s2][sm.b.gidx[s][t][p]][o];
        out[((size_t)t * BSZ + b) * OO + o] = y;
      }
    }
    __syncthreads();
  }
  if (tid < 48) {
    atomicAdd(&acc_imp[tid], sm.b.impL[tid]);
    atomicAdd(&acc_load[tid], sm.b.loadL[tid]);
  }
}

// one wave per row: logsumexp over D=512, block-sum, one atomic per block
__global__ __launch_bounds__(256) void k_rz(const float* __restrict__ x,
                                            float* __restrict__ rz_acc)
{
  __shared__ float wsum[4];
  const int tid  = threadIdx.x;
  const int wid  = tid >> 6;
  const int lane = tid & 63;
  const int b    = blockIdx.x * 4 + wid;
  const float* row = &x[(size_t)b * DD];
  float4 v0 = *reinterpret_cast<const float4*>(&row[lane * 8]);
  float4 v1 = *reinterpret_cast<const float4*>(&row[lane * 8 + 4]);
  float m = fmaxf(fmaxf(fmaxf(v0.x, v0.y), fmaxf(v0.z, v0.w)),
                  fmaxf(fmaxf(v1.x, v1.y), fmaxf(v1.z, v1.w)));
#pragma unroll
  for (int off = 32; off; off >>= 1) m = fmaxf(m, __shfl_xor(m, off));
  float s = expf(v0.x - m) + expf(v0.y - m) + expf(v0.z - m) + expf(v0.w - m)
          + expf(v1.x - m) + expf(v1.y - m) + expf(v1.z - m) + expf(v1.w - m);
#pragma unroll
  for (int off = 32; off; off >>= 1) s += __shfl_xor(s, off);
  if (lane == 0) wsum[wid] = m + logf(s);
  __syncthreads();
  if (tid == 0) atomicAdd(rz_acc, wsum[0] + wsum[1] + wsum[2] + wsum[3]);
}

__global__ void k_final(const float* __restrict__ acc_imp,
                        const float* __restrict__ acc_load,
                        const float* __restrict__ rz_acc,
                        float* __restrict__ out_tail)
{
  if (threadIdx.x == 0 && blockIdx.x == 0) {
    double lb = 0.0;
    for (int t = 0; t < TT; t++) {
      const float* imp = &acc_imp[t * 16];
      const float* ld  = &acc_load[t * 16];
      double si = 0, sl = 0, dot = 0;
      for (int e2 = 0; e2 < 16; e2++) {
        si += imp[e2]; sl += ld[e2]; dot += (double)imp[e2] * ld[e2];
      }
      double mi = si / 16.0, ml = sl / 16.0;
      double vi = 0, vl = 0;
      for (int e2 = 0; e2 < 16; e2++) {
        double di = imp[e2] - mi, dl = ld[e2] - ml;
        vi += di * di; vl += dl * dl;
      }
      vi /= 15.0; vl /= 15.0;
      double cvi = vi / (mi * mi + 1e-10);
      double cvl = vl / (ml * ml + 1e-10);
      double olmo = 16.0 * dot / (double)BSZ;
      lb += (cvi + cvl) * 0.01 + olmo * 0.01;
    }
    out_tail[0] = (float)lb;
    out_tail[1] = (float)(3.0 * (rz_acc[0] / (double)BSZ) * 0.001);
  }
}

extern "C" void kernel_launch(void* const* d_in, const int* in_sizes, int n_in,
                              void* d_out, int out_size, void* d_ws, size_t ws_size,
                              hipStream_t stream) {
  const float* x  = (const float*)d_in[0];
  const float* wg = (const float*)d_in[1];
  const float* bg = (const float*)d_in[2];
  const float* W1 = (const float*)d_in[3];
  const float* b1 = (const float*)d_in[4];
  const float* W2 = (const float*)d_in[5];
  const float* b2 = (const float*)d_in[6];
  const float* W3 = (const float*)d_in[7];
  const float* b3 = (const float*)d_in[8];
  float* out = (float*)d_out;
  float* acc = (float*)d_ws;  // [0:48) importance, [48:96) load, [96] rz sum

  hipMemsetAsync(d_ws, 0, 97 * sizeof(float), stream);
  k_rz<<<dim3(BSZ / 4), dim3(256), 0, stream>>>(x, acc + 96);
  k_main<<<dim3(BSZ / BM), dim3(256), 0, stream>>>(
      x, wg, bg, W1, b1, W2, b2, W3, b3, out, acc, acc + 48);
  k_final<<<dim3(1), dim3(64), 0, stream>>>(acc, acc + 48, acc + 96,
                                            out + (size_t)TT * BSZ * OO);
}

// Round 2
// 744.818 us; speedup vs baseline: 2.8229x; 2.8229x over previous
//
#include <hip/hip_runtime.h>
#include <hip/hip_bf16.h>

#define BSZ   32768
#define DD    512
#define EE    16
#define TT    3
#define KTOP  4
#define OO    16

#define BM    64      // rows per block
#define HM    32      // rows per phase-b half
#define NP    324     // padded W-tile row stride (conflict-free staging)
#define NCOL  304     // 256 expert h1 cols + 48 gate cols
#define BKT   16      // K tile
#define H1PAD 260     // h1s row stride in ushorts (keeps 8B alignment)

__device__ __forceinline__ float bf2f(unsigned short u) {
  return __uint_as_float(((unsigned int)u) << 16);
}
__device__ __forceinline__ unsigned short f2bf(float f) {
  unsigned int u = __float_as_uint(f);
  u += 0x7fffu + ((u >> 16) & 1u);
  return (unsigned short)(u >> 16);
}

union Smem {
  struct {                       // GEMM phase
    float xs[BKT][BM + 4];       // x tile transposed [k][row], pad 4 (bank-spread)
    float wst[BKT][NP];          // W tile [k][c]
  } a;
  struct {                       // tail phase (one 32-row half at a time)
    unsigned short h1s[HM][H1PAD];
    float lgs[HM][48];
    float W2t[2048];             // [(k*8+j)*16+e]
    float W3t[2048];             // [(j*16+o)*16+e]
    float b2t[128];
    float b3t[256];
    float eoL[16][EE][17];
    float gval[HM][TT][KTOP];
    int   gidx[HM][TT][KTOP];
    float impL[48];
    float loadL[48];
    int   nresc;
    int   resc[96];
    double resL[16];
  } b;
};

__global__ __launch_bounds__(256, 2) void k_main(
    const float* __restrict__ x,  const float* __restrict__ wg,
    const float* __restrict__ bg, const float* __restrict__ W1,
    const float* __restrict__ b1, const float* __restrict__ W2,
    const float* __restrict__ b2, const float* __restrict__ W3,
    const float* __restrict__ b3, float* __restrict__ out,
    float* __restrict__ acc_imp, float* __restrict__ acc_load,
    float* __restrict__ rz_acc)
{
  __shared__ Smem sm;
  const int tid = threadIdx.x;
  const int b0  = blockIdx.x * BM;
  const int tx  = tid & 15;     // col group: cols tx*20 .. tx*20+19
  const int ty  = tid >> 4;     // row base: rows ty, ty+16, ty+32, ty+48
  const int l16 = tid & 15;     // staging lane
  const int kks = tid >> 4;     // staging k row

  float acc[4][20];
#pragma unroll
  for (int i = 0; i < 4; i++)
#pragma unroll
    for (int j = 0; j < 20; j++) acc[i][j] = 0.f;

  // online logsumexp state (row = tid&63, k-quarter = tid>>6)
  float rzm = -INFINITY, rzs = 0.f;
  const int rzrow = tid & 63, rzq = tid >> 6;

  for (int k0 = 0; k0 < DD; k0 += BKT) {
    __syncthreads();
    {  // x tile: float4 per thread, transposed store
      const int xr = tid >> 2, xk = (tid & 3) * 4;
      const float4 v = *reinterpret_cast<const float4*>(
          &x[(size_t)(b0 + xr) * DD + k0 + xk]);
      sm.a.xs[xk][xr]     = v.x;
      sm.a.xs[xk + 1][xr] = v.y;
      sm.a.xs[xk + 2][xr] = v.z;
      sm.a.xs[xk + 3][xr] = v.w;
    }
    const int krow = k0 + kks;
#pragma unroll
    for (int rep = 0; rep < 4; rep++) {  // expert W1 cols: c = rep*64 + l16*4
      const float4 w = *reinterpret_cast<const float4*>(
          &W1[(size_t)(rep * 4 + (l16 >> 2)) * 8192 + (size_t)krow * 16 + (l16 & 3) * 4]);
      *reinterpret_cast<float4*>(&sm.a.wst[kks][rep * 64 + l16 * 4]) = w;
    }
    {  // gate cols: c = 256 + l16*4 (lanes >= 12 write zero pad)
      float4 w = make_float4(0.f, 0.f, 0.f, 0.f);
      if (l16 < 12)
        w = *reinterpret_cast<const float4*>(
            &wg[(size_t)(l16 >> 2) * 8192 + (size_t)krow * 16 + (l16 & 3) * 4]);
      *reinterpret_cast<float4*>(&sm.a.wst[kks][256 + l16 * 4]) = w;
    }
    __syncthreads();
#pragma unroll
    for (int k2 = 0; k2 < BKT; k2++) {
      const float xv0 = sm.a.xs[k2][ty];
      const float xv1 = sm.a.xs[k2][ty + 16];
      const float xv2 = sm.a.xs[k2][ty + 32];
      const float xv3 = sm.a.xs[k2][ty + 48];
      const float* wrow = &sm.a.wst[k2][tx * 20];
#pragma unroll
      for (int j = 0; j < 20; j++) {
        const float w = wrow[j];
        acc[0][j] += xv0 * w;
        acc[1][j] += xv1 * w;
        acc[2][j] += xv2 * w;
        acc[3][j] += xv3 * w;
      }
    }
    {  // fused router-z: online logsumexp over this tile's 4 k-values
      const float v0 = sm.a.xs[rzq * 4 + 0][rzrow];
      const float v1 = sm.a.xs[rzq * 4 + 1][rzrow];
      const float v2 = sm.a.xs[rzq * 4 + 2][rzrow];
      const float v3 = sm.a.xs[rzq * 4 + 3][rzrow];
      const float tm = fmaxf(fmaxf(v0, v1), fmaxf(v2, v3));
      const float nm = fmaxf(rzm, tm);
      rzs = rzs * __expf(rzm - nm) + __expf(v0 - nm) + __expf(v1 - nm)
          + __expf(v2 - nm) + __expf(v3 - nm);
      rzm = nm;
    }
  }
  __syncthreads();
  {  // merge rz partials (scratch in dead GEMM-phase xs region)
    float* scr = &sm.a.xs[0][0];
    scr[tid] = rzm;
    scr[256 + tid] = rzs;
    __syncthreads();
    if (tid < 64) {
      const float m0 = scr[tid], m1 = scr[64 + tid], m2 = scr[128 + tid], m3 = scr[192 + tid];
      const float s0 = scr[256 + tid], s1 = scr[320 + tid], s2 = scr[384 + tid], s3 = scr[448 + tid];
      const float M = fmaxf(fmaxf(m0, m1), fmaxf(m2, m3));
      const float S = s0 * __expf(m0 - M) + s1 * __expf(m1 - M)
                    + s2 * __expf(m2 - M) + s3 * __expf(m3 - M);
      float lse = M + __logf(S);
#pragma unroll
      for (int off = 32; off; off >>= 1) lse += __shfl_xor(lse, off);
      if (tid == 0) atomicAdd(rz_acc, lse);
    }
    __syncthreads();
  }

#pragma unroll
  for (int h = 0; h < 2; h++) {
    // ---- epilogue: h1 (relu, bf16) + logits for rows [32h, 32h+32) ----
#pragma unroll
    for (int i = 0; i < 2; i++) {
      const int r = ty + 16 * i;
      const float* a2 = acc[2 * h + i];
#pragma unroll
      for (int j = 0; j < 20; j++) {
        const int c = tx * 20 + j;
        const float v = a2[j];
        if (c < 256) {
          sm.b.h1s[r][c] = f2bf(fmaxf(v + b1[c], 0.f));
        } else if (c < NCOL) {
          sm.b.lgs[r][c - 256] = v + bg[c - 256];
        }
      }
    }
    for (int d = tid; d < 2048; d += 256) {
      sm.b.W2t[d] = W2[(d & 15) * 128 + (d >> 4)];
      sm.b.W3t[d] = W3[(d & 15) * 128 + (d >> 4)];
    }
    if (tid < 128) sm.b.b2t[tid] = b2[(tid & 15) * 8 + (tid >> 4)];
    sm.b.b3t[tid] = b3[(tid & 15) * 16 + (tid >> 4)];
    if (h == 0 && tid < 48) { sm.b.impL[tid] = 0.f; sm.b.loadL[tid] = 0.f; }
    if (tid == 0) sm.b.nresc = 0;
    __syncthreads();

    // ---- gating: 96 threads = 3 tasks x 32 rows ----
    if (tid < 96) {
      const int t = tid >> 5;
      const int s = tid & 31;
      float v[16];
#pragma unroll
      for (int e = 0; e < 16; e++) v[e] = sm.b.lgs[s][t * 16 + e];
      int idx[5]; float val[5];
#pragma unroll
      for (int p = 0; p < 5; p++) {
        float best = -INFINITY; int bi = 0;
#pragma unroll
        for (int e = 0; e < 16; e++)
          if (v[e] > best) { best = v[e]; bi = e; }
        idx[p] = bi; val[p] = best; v[bi] = -INFINITY;
      }
      if (val[3] - val[4] < 1e-3f) {  // ambiguous 4th/5th: defer to f64 rescue
        const int slot = atomicAdd(&sm.b.nresc, 1);
        sm.b.resc[slot] = (s << 2) | t;
      }
      const float m = val[0];
      float ex[4], sum = 0.f;
#pragma unroll
      for (int p = 0; p < 4; p++) { ex[p] = __expf(val[p] - m); sum += ex[p]; }
#pragma unroll
      for (int p = 0; p < 4; p++) {
        const float g = ex[p] / sum;
        sm.b.gval[s][t][p] = g;
        sm.b.gidx[s][t][p] = idx[p];
        atomicAdd(&sm.b.impL[t * 16 + idx[p]], g);
        atomicAdd(&sm.b.loadL[t * 16 + idx[p]], 1.f);
      }
    }
    __syncthreads();

    // ---- cooperative f64 rescue (rare: ~0.3% of rows) ----
    const int nr = sm.b.nresc;
    for (int i = 0; i < nr; i++) {
      const int st = sm.b.resc[i];
      const int s = st >> 2, t = st & 3;
      const int e = tid >> 4, part = tid & 15;
      const float* xr2 = &x[(size_t)(b0 + h * HM + s) * DD];
      const float* wgc = &wg[(size_t)t * DD * EE + e];
      double a = 0.0;
      for (int d = part * 32; d < part * 32 + 32; d++)
        a += (double)xr2[d] * (double)wgc[(size_t)d * EE];
#pragma unroll
      for (int off = 1; off < 16; off <<= 1) a += __shfl_xor(a, off);
      if (part == 0) sm.b.resL[e] = a + (double)bg[t * EE + e];
      __syncthreads();
      if (tid == 0) {
        for (int p = 0; p < KTOP; p++) {  // retract provisional contributions
          sm.b.impL[t * 16 + sm.b.gidx[s][t][p]] -= sm.b.gval[s][t][p];
          sm.b.loadL[t * 16 + sm.b.gidx[s][t][p]] -= 1.f;
        }
        double vv[16];
        for (int e2 = 0; e2 < 16; e2++) vv[e2] = sm.b.resL[e2];
        int idx[4]; float val[4];
        for (int p = 0; p < 4; p++) {
          double best = -1e300; int bi = 0;
          for (int e2 = 0; e2 < 16; e2++)
            if (vv[e2] > best) { best = vv[e2]; bi = e2; }
          idx[p] = bi; val[p] = (float)best; vv[bi] = -1e300;
        }
        const float m = val[0];
        float ex[4], sum = 0.f;
        for (int p = 0; p < 4; p++) { ex[p] = __expf(val[p] - m); sum += ex[p]; }
        for (int p = 0; p < 4; p++) {
          const float g = ex[p] / sum;
          sm.b.gval[s][t][p] = g;
          sm.b.gidx[s][t][p] = idx[p];
          sm.b.impL[t * 16 + idx[p]] += g;
          sm.b.loadL[t * 16 + idx[p]] += 1.f;
        }
      }
      __syncthreads();
    }

    // ---- expert tail + combine: two 16-row subhalves ----
    const int e  = tid & 15;
    const int s2 = tid >> 4;
#pragma unroll
    for (int sh = 0; sh < 2; sh++) {
      const int s = sh * 16 + s2;
      float h1v[16];
#pragma unroll
      for (int q = 0; q < 4; q++) {
        const ushort4 u = *reinterpret_cast<const ushort4*>(&sm.b.h1s[s][e * 16 + q * 4]);
        h1v[q * 4 + 0] = bf2f(u.x);
        h1v[q * 4 + 1] = bf2f(u.y);
        h1v[q * 4 + 2] = bf2f(u.z);
        h1v[q * 4 + 3] = bf2f(u.w);
      }
      float h2v[8];
#pragma unroll
      for (int j = 0; j < 8; j++) {
        float a = sm.b.b2t[j * 16 + e];
#pragma unroll
        for (int k = 0; k < 16; k++) a += h1v[k] * sm.b.W2t[(k * 8 + j) * 16 + e];
        h2v[j] = fmaxf(a, 0.f);
      }
#pragma unroll
      for (int o = 0; o < 16; o++) {
        float a = sm.b.b3t[o * 16 + e];
#pragma unroll
        for (int j = 0; j < 8; j++) a += h2v[j] * sm.b.W3t[(j * 16 + o) * 16 + e];
        sm.b.eoL[s2][e][o] = fmaxf(a, 0.f);
      }
      __syncthreads();
      {
        const int o = e;
        const size_t b = b0 + h * HM + s;
#pragma unroll
        for (int t = 0; t < TT; t++) {
          float y = 0.f;
#pragma unroll
          for (int p = 0; p < KTOP; p++)
            y += sm.b.gval[s][t][p] * sm.b.eoL[s2][sm.b.gidx[s][t][p]][o];
          out[((size_t)t * BSZ + b) * OO + o] = y;
        }
      }
      __syncthreads();
    }
  }
  if (tid < 48) {
    atomicAdd(&acc_imp[tid], sm.b.impL[tid]);
    atomicAdd(&acc_load[tid], sm.b.loadL[tid]);
  }
}

__global__ void k_final(const float* __restrict__ acc_imp,
                        const float* __restrict__ acc_load,
                        const float* __restrict__ rz_acc,
                        float* __restrict__ out_tail)
{
  if (threadIdx.x == 0 && blockIdx.x == 0) {
    double lb = 0.0;
    for (int t = 0; t < TT; t++) {
      const float* imp = &acc_imp[t * 16];
      const float* ld  = &acc_load[t * 16];
      double si = 0, sl = 0, dot = 0;
      for (int e2 = 0; e2 < 16; e2++) {
        si += imp[e2]; sl += ld[e2]; dot += (double)imp[e2] * ld[e2];
      }
      double mi = si / 16.0, ml = sl / 16.0;
      double vi = 0, vl = 0;
      for (int e2 = 0; e2 < 16; e2++) {
        double di = imp[e2] - mi, dl = ld[e2] - ml;
        vi += di * di; vl += dl * dl;
      }
      vi /= 15.0; vl /= 15.0;
      double cvi = vi / (mi * mi + 1e-10);
      double cvl = vl / (ml * ml + 1e-10);
      double olmo = 16.0 * dot / (double)BSZ;
      lb += (cvi + cvl) * 0.01 + olmo * 0.01;
    }
    out_tail[0] = (float)lb;
    out_tail[1] = (float)(3.0 * (rz_acc[0] / (double)BSZ) * 0.001);
  }
}

extern "C" void kernel_launch(void* const* d_in, const int* in_sizes, int n_in,
                              void* d_out, int out_size, void* d_ws, size_t ws_size,
                              hipStream_t stream) {
  const float* x  = (const float*)d_in[0];
  const float* wg = (const float*)d_in[1];
  const float* bg = (const float*)d_in[2];
  const float* W1 = (const float*)d_in[3];
  const float* b1 = (const float*)d_in[4];
  const float* W2 = (const float*)d_in[5];
  const float* b2 = (const float*)d_in[6];
  const float* W3 = (const float*)d_in[7];
  const float* b3 = (const float*)d_in[8];
  float* out = (float*)d_out;
  float* acc = (float*)d_ws;  // [0:48) importance, [48:96) load, [96] rz sum

  hipMemsetAsync(d_ws, 0, 97 * sizeof(float), stream);
  k_main<<<dim3(BSZ / BM), dim3(256), 0, stream>>>(
      x, wg, bg, W1, b1, W2, b2, W3, b3, out, acc, acc + 48, acc + 96);
  k_final<<<dim3(1), dim3(64), 0, stream>>>(acc, acc + 48, acc + 96,
                                            out + (size_t)TT * BSZ * OO);
}

// Round 3
// 324.186 us; speedup vs baseline: 6.4856x; 2.2975x over previous
//
#include <hip/hip_runtime.h>
#include <hip/hip_bf16.h>

#define BSZ 32768
#define DD  512
#define TT  3
#define OO  16

typedef __attribute__((ext_vector_type(8))) short bf16x8;
typedef __attribute__((ext_vector_type(4))) float f32x4;

__device__ __forceinline__ float bf2f(unsigned short u) {
  return __uint_as_float(((unsigned)u) << 16);
}
__device__ __forceinline__ unsigned short f2bf(float f) {
  unsigned u = __float_as_uint(f);
  u += 0x7fffu + ((u >> 16) & 1u);
  return (unsigned short)(u >> 16);
}
__device__ __forceinline__ unsigned pack2(unsigned short a, unsigned short b) {
  return (unsigned)a | ((unsigned)b << 16);
}

// ---- build split-precision transposed weights: Wt[n][k], n<256: W1, 256..303: wg, 304+: 0
__global__ void k_prepw(const float* __restrict__ W1, const float* __restrict__ wg,
                        unsigned short* __restrict__ Wth, unsigned short* __restrict__ Wtl) {
  for (int idx = blockIdx.x * 256 + threadIdx.x; idx < 320 * 512;
       idx += gridDim.x * 256) {
    const int n = idx >> 9, k = idx & 511;
    float v = 0.f;
    if (n < 256) v = W1[(size_t)(n >> 4) * 8192 + k * 16 + (n & 15)];
    else if (n < 304) { int m = n - 256; v = wg[(size_t)(m >> 4) * 8192 + k * 16 + (m & 15)]; }
    const unsigned short hi = f2bf(v);
    const unsigned short lo = f2bf(v - bf2f(hi));
    Wth[idx] = hi; Wtl[idx] = lo;
  }
}

struct GemmSmem {
  union {
    struct {
      unsigned short xh[64][32];    // 4 KB
      unsigned short xl[64][32];    // 4 KB
      unsigned short wh[320][32];   // 20 KB
      unsigned short wl[320][32];   // 20 KB
    } a;
    struct {
      unsigned short hdump[64][264];  // 33.8 KB (repack h1 for coalesced stores)
    } b;
  } u;
  float rzscr[64];
};

// M=64/block, N=320 (256 h1 + 48 logits + 16 pad), K=512, 3-pass split-bf16 MFMA
__global__ __launch_bounds__(256, 2) void k_gemm(
    const float* __restrict__ x, const unsigned short* __restrict__ Wth,
    const unsigned short* __restrict__ Wtl, const float* __restrict__ b1,
    const float* __restrict__ bg, unsigned short* __restrict__ h1b,
    float* __restrict__ lgits, float* __restrict__ rz_acc) {
  __shared__ GemmSmem sm;
  const int tid = threadIdx.x;
  const int b0 = blockIdx.x * 64;
  const int l = tid & 63, w = tid >> 6;
  const int l15 = l & 15, quad = l >> 4;
  const int xr = tid >> 2, xks = tid & 3;

  f32x4 acc[4][5];
#pragma unroll
  for (int m = 0; m < 4; m++)
#pragma unroll
    for (int c = 0; c < 5; c++) acc[m][c] = (f32x4){0.f, 0.f, 0.f, 0.f};

  float rzm = -INFINITY, rzs = 0.f;
  float4 xa, xb;
  uint4 whr[5], wlr[5];

  auto load_tile = [&](int it) {
    const float* xp = &x[(size_t)(b0 + xr) * 512 + it * 32 + xks * 8];
    xa = *(const float4*)xp;
    xb = *(const float4*)(xp + 4);
#pragma unroll
    for (int i = 0; i < 5; i++) {
      const int u2 = i * 256 + tid;
      const size_t off = (size_t)(u2 >> 2) * 512 + it * 32 + (u2 & 3) * 8;
      whr[i] = *(const uint4*)&Wth[off];
      wlr[i] = *(const uint4*)&Wtl[off];
    }
  };
  auto store_tile = [&]() {
    float v[8] = {xa.x, xa.y, xa.z, xa.w, xb.x, xb.y, xb.z, xb.w};
    float tm = v[0];
#pragma unroll
    for (int j = 1; j < 8; j++) tm = fmaxf(tm, v[j]);
    const float nm = fmaxf(rzm, tm);
    float s = 0.f;
#pragma unroll
    for (int j = 0; j < 8; j++) s += __expf(v[j] - nm);
    rzs = rzs * __expf(rzm - nm) + s;
    rzm = nm;
    unsigned short hh[8], ll[8];
#pragma unroll
    for (int j = 0; j < 8; j++) {
      hh[j] = f2bf(v[j]);
      ll[j] = f2bf(v[j] - bf2f(hh[j]));
    }
    uint4 ph, pl;
    ph.x = pack2(hh[0], hh[1]); ph.y = pack2(hh[2], hh[3]);
    ph.z = pack2(hh[4], hh[5]); ph.w = pack2(hh[6], hh[7]);
    pl.x = pack2(ll[0], ll[1]); pl.y = pack2(ll[2], ll[3]);
    pl.z = pack2(ll[4], ll[5]); pl.w = pack2(ll[6], ll[7]);
    *(uint4*)&sm.u.a.xh[xr][xks * 8] = ph;
    *(uint4*)&sm.u.a.xl[xr][xks * 8] = pl;
#pragma unroll
    for (int i = 0; i < 5; i++) {
      const int u2 = i * 256 + tid;
      *(uint4*)&sm.u.a.wh[u2 >> 2][(u2 & 3) * 8] = whr[i];
      *(uint4*)&sm.u.a.wl[u2 >> 2][(u2 & 3) * 8] = wlr[i];
    }
  };

  load_tile(0);
  for (int it = 0; it < 16; ++it) {
    __syncthreads();
    store_tile();
    __syncthreads();
    if (it < 15) load_tile(it + 1);
    bf16x8 ah[4], al[4];
#pragma unroll
    for (int m = 0; m < 4; m++) {
      ah[m] = *(const bf16x8*)&sm.u.a.xh[16 * m + l15][quad * 8];
      al[m] = *(const bf16x8*)&sm.u.a.xl[16 * m + l15][quad * 8];
    }
#pragma unroll
    for (int c = 0; c < 5; c++) {
      const int n = 80 * w + 16 * c + l15;
      const bf16x8 bh = *(const bf16x8*)&sm.u.a.wh[n][quad * 8];
      const bf16x8 bl = *(const bf16x8*)&sm.u.a.wl[n][quad * 8];
#pragma unroll
      for (int m = 0; m < 4; m++) {
        acc[m][c] = __builtin_amdgcn_mfma_f32_16x16x32_bf16(ah[m], bh, acc[m][c], 0, 0, 0);
        acc[m][c] = __builtin_amdgcn_mfma_f32_16x16x32_bf16(al[m], bh, acc[m][c], 0, 0, 0);
        acc[m][c] = __builtin_amdgcn_mfma_f32_16x16x32_bf16(ah[m], bl, acc[m][c], 0, 0, 0);
      }
    }
  }
  // merge rz across the 4 threads sharing a row (lanes t^1, t^2 — same wave)
#pragma unroll
  for (int off = 1; off <= 2; off <<= 1) {
    const float om = __shfl_xor(rzm, off), os = __shfl_xor(rzs, off);
    const float nm = fmaxf(rzm, om);
    rzs = rzs * __expf(rzm - nm) + os * __expf(om - nm);
    rzm = nm;
  }
  if ((tid & 3) == 0) sm.rzscr[tid >> 2] = rzm + __logf(rzs);
  __syncthreads();  // also guarantees all MFMA LDS reads done before hdump reuse
  if (tid < 64) {
    float vv = sm.rzscr[tid];
#pragma unroll
    for (int off = 32; off; off >>= 1) vv += __shfl_xor(vv, off);
    if (tid == 0) atomicAdd(rz_acc, vv);
  }
  // epilogue: h1 -> LDS repack; logits -> direct scalar f32 stores (wave 3 only)
#pragma unroll
  for (int m = 0; m < 4; m++)
#pragma unroll
    for (int c = 0; c < 5; c++) {
      const int col = 80 * w + 16 * c + l15;
#pragma unroll
      for (int reg = 0; reg < 4; reg++) {
        const int row = 16 * m + quad * 4 + reg;
        const float v = acc[m][c][reg];
        if (col < 256) {
          sm.u.b.hdump[row][col] = f2bf(fmaxf(v + b1[col], 0.f));
        } else if (col < 304) {
          lgits[(size_t)(b0 + row) * 48 + (col - 256)] = v + bg[col - 256];
        }
      }
    }
  __syncthreads();
#pragma unroll
  for (int i = 0; i < 8; i++) {
    const int u2 = i * 256 + tid;
    const int row = u2 >> 5, seg = u2 & 31;
    *(uint4*)&h1b[(size_t)(b0 + row) * 256 + seg * 8] =
        *(const uint4*)&sm.u.b.hdump[row][seg * 8];
  }
}

// top-5 / softmax / rescue / load-balance stats
__global__ __launch_bounds__(256) void k_gate(
    const float* __restrict__ lgits, const float* __restrict__ x,
    const float* __restrict__ wg, const float* __restrict__ bg,
    float* __restrict__ gval, int* __restrict__ gidx,
    float* __restrict__ acc_imp, float* __restrict__ acc_load) {
  __shared__ float impL[48], loadL[48];
  __shared__ int nresc, resc[192];
  __shared__ double resL[16];
  __shared__ float gvP[64][12];
  __shared__ int giP[64][12];
  const int tid = threadIdx.x;
  const int b0 = blockIdx.x * 64;
  if (tid < 48) { impL[tid] = 0.f; loadL[tid] = 0.f; }
  if (tid == 0) nresc = 0;
  __syncthreads();
  if (tid < 192) {
    const int r = tid & 63, tk = tid >> 6;
    const float* lp = &lgits[(size_t)(b0 + r) * 48 + tk * 16];
    const float4 q0 = *(const float4*)lp, q1 = *(const float4*)(lp + 4);
    const float4 q2 = *(const float4*)(lp + 8), q3 = *(const float4*)(lp + 12);
    float v[16] = {q0.x, q0.y, q0.z, q0.w, q1.x, q1.y, q1.z, q1.w,
                   q2.x, q2.y, q2.z, q2.w, q3.x, q3.y, q3.z, q3.w};
    int idx[5]; float val[5];
#pragma unroll
    for (int p = 0; p < 5; p++) {
      float best = -INFINITY; int bi = 0;
#pragma unroll
      for (int e = 0; e < 16; e++)
        if (v[e] > best) { best = v[e]; bi = e; }
      idx[p] = bi; val[p] = best; v[bi] = -INFINITY;
    }
    if (val[3] - val[4] < 1e-3f) {
      const int s = atomicAdd(&nresc, 1);
      resc[s] = (r << 2) | tk;
    }
    const float m = val[0];
    float ex[4], sum = 0.f;
#pragma unroll
    for (int p = 0; p < 4; p++) { ex[p] = __expf(val[p] - m); sum += ex[p]; }
#pragma unroll
    for (int p = 0; p < 4; p++) {
      const float g = ex[p] / sum;
      gvP[r][tk * 4 + p] = g;
      giP[r][tk * 4 + p] = idx[p];
      atomicAdd(&impL[tk * 16 + idx[p]], g);
      atomicAdd(&loadL[tk * 16 + idx[p]], 1.f);
    }
  }
  __syncthreads();
  const int nr = nresc;
  for (int i = 0; i < nr; i++) {
    const int st = resc[i];
    const int r = st >> 2, tk = st & 3;
    const int e = tid >> 4, part = tid & 15;
    const float* xr2 = &x[(size_t)(b0 + r) * 512];
    const float* wgc = &wg[(size_t)tk * 8192 + e];
    double a = 0.0;
    for (int d = part * 32; d < part * 32 + 32; d++)
      a += (double)xr2[d] * (double)wgc[(size_t)d * 16];
#pragma unroll
    for (int off = 1; off < 16; off <<= 1) a += __shfl_xor(a, off);
    if (part == 0) resL[e] = a + (double)bg[tk * 16 + e];
    __syncthreads();
    if (tid == 0) {
      for (int p = 0; p < 4; p++) {
        impL[tk * 16 + giP[r][tk * 4 + p]] -= gvP[r][tk * 4 + p];
        loadL[tk * 16 + giP[r][tk * 4 + p]] -= 1.f;
      }
      double vv[16];
      for (int e2 = 0; e2 < 16; e2++) vv[e2] = resL[e2];
      int idx[4]; float val[4];
      for (int p = 0; p < 4; p++) {
        double best = -1e300; int bi = 0;
        for (int e2 = 0; e2 < 16; e2++)
          if (vv[e2] > best) { best = vv[e2]; bi = e2; }
        idx[p] = bi; val[p] = (float)best; vv[bi] = -1e300;
      }
      const float m = val[0];
      float ex[4], sum = 0.f;
      for (int p = 0; p < 4; p++) { ex[p] = __expf(val[p] - m); sum += ex[p]; }
      for (int p = 0; p < 4; p++) {
        const float g = ex[p] / sum;
        gvP[r][tk * 4 + p] = g;
        giP[r][tk * 4 + p] = idx[p];
        impL[tk * 16 + idx[p]] += g;
        loadL[tk * 16 + idx[p]] += 1.f;
      }
    }
    __syncthreads();
  }
  if (tid < 192) {
    const int r = tid & 63, tk = tid >> 6;
    const float4 gq = make_float4(gvP[r][tk * 4], gvP[r][tk * 4 + 1],
                                  gvP[r][tk * 4 + 2], gvP[r][tk * 4 + 3]);
    const int4 iq = make_int4(giP[r][tk * 4], giP[r][tk * 4 + 1],
                              giP[r][tk * 4 + 2], giP[r][tk * 4 + 3]);
    *(float4*)&gval[(size_t)(b0 + r) * 12 + tk * 4] = gq;
    *(int4*)&gidx[(size_t)(b0 + r) * 12 + tk * 4] = iq;
  }
  if (tid < 48) {
    atomicAdd(&acc_imp[tid], impL[tid]);
    atomicAdd(&acc_load[tid], loadL[tid]);
  }
}

// expert tail MLP + gated combine
__global__ __launch_bounds__(256) void k_tail(
    const unsigned short* __restrict__ h1b, const float* __restrict__ gval,
    const int* __restrict__ gidx, const float* __restrict__ W2,
    const float* __restrict__ b2, const float* __restrict__ W3,
    const float* __restrict__ b3, float* __restrict__ out) {
  __shared__ float W2t[2048], W3t[2048], b2t[128], b3t[256];
  __shared__ float eoL[16][16][17];
  __shared__ float gvL[32][12];
  __shared__ int giL[32][12];
  const int tid = threadIdx.x;
  const int b0 = blockIdx.x * 32;
  for (int d = tid; d < 2048; d += 256) {
    W2t[d] = W2[(d & 15) * 128 + (d >> 4)];
    W3t[d] = W3[(d & 15) * 128 + (d >> 4)];
  }
  if (tid < 128) b2t[tid] = b2[(tid & 15) * 8 + (tid >> 4)];
  b3t[tid] = b3[(tid & 15) * 16 + (tid >> 4)];
  if (tid < 96) {
    *(float4*)&((float*)gvL)[tid * 4] = *(const float4*)&gval[(size_t)b0 * 12 + tid * 4];
    *(int4*)&((int*)giL)[tid * 4] = *(const int4*)&gidx[(size_t)b0 * 12 + tid * 4];
  }
  __syncthreads();
  const int e = tid & 15, sr = tid >> 4;
  for (int sh = 0; sh < 2; ++sh) {
    const int s = sh * 16 + sr;
    const uint4 u0 = *(const uint4*)&h1b[(size_t)(b0 + s) * 256 + e * 16];
    const uint4 u1 = *(const uint4*)&h1b[(size_t)(b0 + s) * 256 + e * 16 + 8];
    float h1v[16];
    {
      const unsigned uu[8] = {u0.x, u0.y, u0.z, u0.w, u1.x, u1.y, u1.z, u1.w};
#pragma unroll
      for (int j = 0; j < 8; j++) {
        h1v[2 * j] = bf2f((unsigned short)(uu[j] & 0xffffu));
        h1v[2 * j + 1] = bf2f((unsigned short)(uu[j] >> 16));
      }
    }
    float h2v[8];
#pragma unroll
    for (int j = 0; j < 8; j++) {
      float a = b2t[j * 16 + e];
#pragma unroll
      for (int k = 0; k < 16; k++) a += h1v[k] * W2t[(k * 8 + j) * 16 + e];
      h2v[j] = fmaxf(a, 0.f);
    }
#pragma unroll
    for (int o = 0; o < 16; o++) {
      float a = b3t[o * 16 + e];
#pragma unroll
      for (int j = 0; j < 8; j++) a += h2v[j] * W3t[(j * 16 + o) * 16 + e];
      eoL[sr][e][o] = fmaxf(a, 0.f);
    }
    __syncthreads();
    {
      const int o = e;
#pragma unroll
      for (int tk = 0; tk < TT; tk++) {
        float y = 0.f;
#pragma unroll
        for (int p = 0; p < 4; p++)
          y += gvL[s][tk * 4 + p] * eoL[sr][giL[s][tk * 4 + p]][o];
        out[((size_t)tk * BSZ + b0 + s) * OO + o] = y;
      }
    }
    __syncthreads();
  }
}

__global__ void k_final(const float* __restrict__ acc_imp,
                        const float* __restrict__ acc_load,
                        const float* __restrict__ rz_acc,
                        float* __restrict__ out_tail) {
  if (threadIdx.x == 0 && blockIdx.x == 0) {
    double lb = 0.0;
    for (int t = 0; t < TT; t++) {
      const float* imp = &acc_imp[t * 16];
      const float* ld = &acc_load[t * 16];
      double si = 0, sl = 0, dot = 0;
      for (int e2 = 0; e2 < 16; e2++) {
        si += imp[e2]; sl += ld[e2]; dot += (double)imp[e2] * ld[e2];
      }
      const double mi = si / 16.0, ml = sl / 16.0;
      double vi = 0, vl = 0;
      for (int e2 = 0; e2 < 16; e2++) {
        const double di = imp[e2] - mi, dl = ld[e2] - ml;
        vi += di * di; vl += dl * dl;
      }
      vi /= 15.0; vl /= 15.0;
      lb += (vi / (mi * mi + 1e-10) + vl / (ml * ml + 1e-10)) * 0.01
          + 16.0 * dot / (double)BSZ * 0.01;
    }
    out_tail[0] = (float)lb;
    out_tail[1] = (float)(3.0 * (rz_acc[0] / (double)BSZ) * 0.001);
  }
}

extern "C" void kernel_launch(void* const* d_in, const int* in_sizes, int n_in,
                              void* d_out, int out_size, void* d_ws, size_t ws_size,
                              hipStream_t stream) {
  const float* x  = (const float*)d_in[0];
  const float* wg = (const float*)d_in[1];
  const float* bg = (const float*)d_in[2];
  const float* W1 = (const float*)d_in[3];
  const float* b1 = (const float*)d_in[4];
  const float* W2 = (const float*)d_in[5];
  const float* b2 = (const float*)d_in[6];
  const float* W3 = (const float*)d_in[7];
  const float* b3 = (const float*)d_in[8];
  float* out = (float*)d_out;

  char* wsb = (char*)d_ws;
  unsigned short* Wth = (unsigned short*)wsb;                 //   327,680 B
  unsigned short* Wtl = (unsigned short*)(wsb + 327680);      //   327,680 B
  unsigned short* h1b = (unsigned short*)(wsb + 655360);      // 16,777,216 B
  float* lgits = (float*)(wsb + 17432576);                    //  6,291,456 B
  float* gval  = (float*)(wsb + 23724032);                    //  1,572,864 B
  int*   gidx  = (int*)(wsb + 25296896);                      //  1,572,864 B
  float* acc   = (float*)(wsb + 26869760);                    // 97 floats

  hipMemsetAsync(acc, 0, 97 * sizeof(float), stream);
  k_prepw<<<dim3(160), dim3(256), 0, stream>>>(W1, wg, Wth, Wtl);
  k_gemm<<<dim3(BSZ / 64), dim3(256), 0, stream>>>(x, Wth, Wtl, b1, bg, h1b, lgits,
                                                   acc + 96);
  k_gate<<<dim3(BSZ / 64), dim3(256), 0, stream>>>(lgits, x, wg, bg, gval, gidx,
                                                   acc, acc + 48);
  k_tail<<<dim3(BSZ / 32), dim3(256), 0, stream>>>(h1b, gval, gidx, W2, b2, W3, b3,
                                                   out);
  k_final<<<dim3(1), dim3(64), 0, stream>>>(acc, acc + 48, acc + 96,
                                            out + (size_t)TT * BSZ * OO);
}

// Round 4
// 295.841 us; speedup vs baseline: 7.1070x; 1.0958x over previous
//
#include <hip/hip_runtime.h>
#include <hip/hip_bf16.h>

#define BSZ 32768
#define DD  512
#define TT  3
#define OO  16

typedef __attribute__((ext_vector_type(8))) short bf16x8;
typedef __attribute__((ext_vector_type(4))) float f32x4;

__device__ __forceinline__ float bf2f(unsigned short u) {
  return __uint_as_float(((unsigned)u) << 16);
}
__device__ __forceinline__ unsigned short f2bf(float f) {
  unsigned u = __float_as_uint(f);
  u += 0x7fffu + ((u >> 16) & 1u);
  return (unsigned short)(u >> 16);
}
__device__ __forceinline__ unsigned pack2(unsigned short a, unsigned short b) {
  return (unsigned)a | ((unsigned)b << 16);
}

// Wth[n][k]: n<256 = W1 transposed, 256..303 = w_gates, 304..319 = 0. Also zero acc.
__global__ void k_prepw(const float* __restrict__ W1, const float* __restrict__ wg,
                        unsigned short* __restrict__ Wth, float* __restrict__ acc) {
  if (blockIdx.x == 0 && threadIdx.x < 97) acc[threadIdx.x] = 0.f;
  for (int idx = blockIdx.x * 256 + threadIdx.x; idx < 320 * 512;
       idx += gridDim.x * 256) {
    const int n = idx >> 9, k = idx & 511;
    float v = 0.f;
    if (n < 256) v = W1[(size_t)(n >> 4) * 8192 + k * 16 + (n & 15)];
    else if (n < 304) { const int m = n - 256; v = wg[(size_t)(m >> 4) * 8192 + k * 16 + (m & 15)]; }
    Wth[idx] = f2bf(v);
  }
}

struct GSmem {
  union {
    struct {
      unsigned short xf[2][2][4][64][8];  // [buf][hi/lo][m][lane][8] — frag order, 16 KB
      float rzscr[64];
    } a;
    struct {
      unsigned short hdump[64][264];  // 33.8 KB
      float lgs[64][52];              // 13.3 KB
      float gv[64][12];
      int   gi[64][12];
      float impL[48], loadL[48];
      int   nresc, resc[192];
      double resL[16];
    } b;
  } u;
};

// M=64/block, N=320 (4 waves x 80 cols), K=512. 2-pass split-bf16 MFMA,
// x staged in LDS (dbuf, fragment-ordered), W direct from L2. Fused rz + gating.
__global__ __launch_bounds__(256, 2) void k_gemm(
    const float* __restrict__ x, const unsigned short* __restrict__ Wth,
    const float* __restrict__ b1, const float* __restrict__ bg,
    const float* __restrict__ wg, unsigned short* __restrict__ h1b,
    float* __restrict__ gval, int* __restrict__ gidx,
    float* __restrict__ acc_imp, float* __restrict__ acc_load,
    float* __restrict__ rz_acc) {
  __shared__ GSmem sm;
  const int tid = threadIdx.x;
  const int b0 = blockIdx.x * 64;
  const int w = tid >> 6, l = tid & 63;
  const int l15 = l & 15, quad = l >> 4;
  const int srow = tid >> 2, sseg = tid & 3;   // staging: row, 8-float k-segment
  const int sm_ = srow >> 4, slane = sseg * 16 + (srow & 15);

  f32x4 acc[4][5];
#pragma unroll
  for (int m = 0; m < 4; m++)
#pragma unroll
    for (int c = 0; c < 5; c++) acc[m][c] = (f32x4){0.f, 0.f, 0.f, 0.f};

  float4 xa, xb;
  bf16x8 bcur[5], bnxt[5];
  float rzsum = 0.f;

  auto load_x = [&](int it) {
    const float* xp = &x[(size_t)(b0 + srow) * 512 + it * 32 + sseg * 8];
    xa = *(const float4*)xp;
    xb = *(const float4*)(xp + 4);
  };
  auto load_b = [&](bf16x8* dst, int it) {
#pragma unroll
    for (int c = 0; c < 5; c++) {
      const int n = 80 * w + 16 * c + l15;
      dst[c] = *(const bf16x8*)&Wth[(size_t)n * 512 + it * 32 + quad * 8];
    }
  };
  auto cvt_store = [&](int buf) {
    const float v[8] = {xa.x, xa.y, xa.z, xa.w, xb.x, xb.y, xb.z, xb.w};
#pragma unroll
    for (int j = 0; j < 8; j++) rzsum += __expf(v[j]);
    unsigned short hh[8], ll[8];
#pragma unroll
    for (int j = 0; j < 8; j++) {
      hh[j] = f2bf(v[j]);
      ll[j] = f2bf(v[j] - bf2f(hh[j]));
    }
    uint4 ph, pl;
    ph.x = pack2(hh[0], hh[1]); ph.y = pack2(hh[2], hh[3]);
    ph.z = pack2(hh[4], hh[5]); ph.w = pack2(hh[6], hh[7]);
    pl.x = pack2(ll[0], ll[1]); pl.y = pack2(ll[2], ll[3]);
    pl.z = pack2(ll[4], ll[5]); pl.w = pack2(ll[6], ll[7]);
    *(uint4*)&sm.u.a.xf[buf][0][sm_][slane][0] = ph;
    *(uint4*)&sm.u.a.xf[buf][1][sm_][slane][0] = pl;
  };

  load_x(0); load_b(bcur, 0);
  cvt_store(0);
  load_x(1); load_b(bnxt, 1);
  __syncthreads();

  for (int it = 0; it < 16; ++it) {
    bf16x8 ah[4], al[4];
    const int buf = it & 1;
#pragma unroll
    for (int m = 0; m < 4; m++) {
      ah[m] = *(const bf16x8*)&sm.u.a.xf[buf][0][m][l][0];
      al[m] = *(const bf16x8*)&sm.u.a.xf[buf][1][m][l][0];
    }
#pragma unroll
    for (int c = 0; c < 5; c++)
#pragma unroll
      for (int m = 0; m < 4; m++) {
        acc[m][c] = __builtin_amdgcn_mfma_f32_16x16x32_bf16(ah[m], bcur[c], acc[m][c], 0, 0, 0);
        acc[m][c] = __builtin_amdgcn_mfma_f32_16x16x32_bf16(al[m], bcur[c], acc[m][c], 0, 0, 0);
      }
    if (it < 15) {
      cvt_store((it + 1) & 1);
#pragma unroll
      for (int c = 0; c < 5; c++) bcur[c] = bnxt[c];
      if (it < 14) { load_x(it + 2); load_b(bnxt, it + 2); }
      __syncthreads();
    }
  }

  // ---- router-z: rzsum covers (row=srow, k ≡ sseg*8 mod 32); merge 4 segs ----
  rzsum += __shfl_xor(rzsum, 1);
  rzsum += __shfl_xor(rzsum, 2);
  if (sseg == 0) sm.u.a.rzscr[srow] = __logf(rzsum);
  __syncthreads();
  if (tid < 64) {
    float vv = sm.u.a.rzscr[tid];
#pragma unroll
    for (int off = 32; off; off >>= 1) vv += __shfl_xor(vv, off);
    if (tid == 0) atomicAdd(rz_acc, vv);
  }
  __syncthreads();  // xf/rzscr dead; reuse union for phase b

  // ---- epilogue: h1 -> hdump (bf16), logits -> lgs ----
#pragma unroll
  for (int m = 0; m < 4; m++)
#pragma unroll
    for (int c = 0; c < 5; c++) {
      const int col = 80 * w + 16 * c + l15;
#pragma unroll
      for (int reg = 0; reg < 4; reg++) {
        const int row = 16 * m + quad * 4 + reg;
        const float v = acc[m][c][reg];
        if (col < 256) sm.u.b.hdump[row][col] = f2bf(fmaxf(v + b1[col], 0.f));
        else if (col < 304) sm.u.b.lgs[row][col - 256] = v + bg[col - 256];
      }
    }
  if (tid < 48) { sm.u.b.impL[tid] = 0.f; sm.u.b.loadL[tid] = 0.f; }
  if (tid == 0) sm.u.b.nresc = 0;
  __syncthreads();

  // h1 coalesced dump
#pragma unroll
  for (int i = 0; i < 8; i++) {
    const int u2 = i * 256 + tid;
    const int row = u2 >> 5, seg = u2 & 31;
    *(uint4*)&h1b[(size_t)(b0 + row) * 256 + seg * 8] =
        *(const uint4*)&sm.u.b.hdump[row][seg * 8];
  }

  // ---- gating: 192 threads = 3 tasks x 64 rows ----
  if (tid < 192) {
    const int r = tid & 63, tk = tid >> 6;
    float v[16];
#pragma unroll
    for (int e = 0; e < 16; e++) v[e] = sm.u.b.lgs[r][tk * 16 + e];
    int idx[5]; float val[5];
#pragma unroll
    for (int p = 0; p < 5; p++) {
      float best = -INFINITY; int bi = 0;
#pragma unroll
      for (int e = 0; e < 16; e++)
        if (v[e] > best) { best = v[e]; bi = e; }
      idx[p] = bi; val[p] = best; v[bi] = -INFINITY;
    }
    if (val[3] - val[4] < 8e-3f) {  // 2-pass logit sigma ~1.3e-3; 6-sigma window
      const int s = atomicAdd(&sm.u.b.nresc, 1);
      sm.u.b.resc[s] = (r << 2) | tk;
    }
    const float m = val[0];
    float ex[4], sum = 0.f;
#pragma unroll
    for (int p = 0; p < 4; p++) { ex[p] = __expf(val[p] - m); sum += ex[p]; }
#pragma unroll
    for (int p = 0; p < 4; p++) {
      const float g = ex[p] / sum;
      sm.u.b.gv[r][tk * 4 + p] = g;
      sm.u.b.gi[r][tk * 4 + p] = idx[p];
      atomicAdd(&sm.u.b.impL[tk * 16 + idx[p]], g);
      atomicAdd(&sm.u.b.loadL[tk * 16 + idx[p]], 1.f);
    }
  }
  __syncthreads();

  // ---- cooperative f64 rescue for ambiguous 4th/5th boundaries ----
  const int nr = sm.u.b.nresc;
  for (int i = 0; i < nr; i++) {
    const int st = sm.u.b.resc[i];
    const int r = st >> 2, tk = st & 3;
    const int e = tid >> 4, part = tid & 15;
    const float* xr2 = &x[(size_t)(b0 + r) * 512];
    const float* wgc = &wg[(size_t)tk * 8192 + e];
    double a = 0.0;
    for (int d = part * 32; d < part * 32 + 32; d++)
      a += (double)xr2[d] * (double)wgc[(size_t)d * 16];
#pragma unroll
    for (int off = 1; off < 16; off <<= 1) a += __shfl_xor(a, off);
    if (part == 0) sm.u.b.resL[e] = a + (double)bg[tk * 16 + e];
    __syncthreads();
    if (tid == 0) {
      for (int p = 0; p < 4; p++) {
        sm.u.b.impL[tk * 16 + sm.u.b.gi[r][tk * 4 + p]] -= sm.u.b.gv[r][tk * 4 + p];
        sm.u.b.loadL[tk * 16 + sm.u.b.gi[r][tk * 4 + p]] -= 1.f;
      }
      double vv[16];
      for (int e2 = 0; e2 < 16; e2++) vv[e2] = sm.u.b.resL[e2];
      int idx[4]; float val[4];
      for (int p = 0; p < 4; p++) {
        double best = -1e300; int bi = 0;
        for (int e2 = 0; e2 < 16; e2++)
          if (vv[e2] > best) { best = vv[e2]; bi = e2; }
        idx[p] = bi; val[p] = (float)best; vv[bi] = -1e300;
      }
      const float m = val[0];
      float ex[4], sum = 0.f;
      for (int p = 0; p < 4; p++) { ex[p] = __expf(val[p] - m); sum += ex[p]; }
      for (int p = 0; p < 4; p++) {
        const float g = ex[p] / sum;
        sm.u.b.gv[r][tk * 4 + p] = g;
        sm.u.b.gi[r][tk * 4 + p] = idx[p];
        sm.u.b.impL[tk * 16 + idx[p]] += g;
        sm.u.b.loadL[tk * 16 + idx[p]] += 1.f;
      }
    }
    __syncthreads();
  }

  if (tid < 192) {
    const int r = tid & 63, tk = tid >> 6;
    *(float4*)&gval[(size_t)(b0 + r) * 12 + tk * 4] = *(const float4*)&sm.u.b.gv[r][tk * 4];
    *(int4*)&gidx[(size_t)(b0 + r) * 12 + tk * 4] = *(const int4*)&sm.u.b.gi[r][tk * 4];
  }
  if (tid < 48) {
    atomicAdd(&acc_imp[tid], sm.u.b.impL[tid]);
    atomicAdd(&acc_load[tid], sm.u.b.loadL[tid]);
  }
}

// expert tail MLP + gated combine: 64 rows/block
__global__ __launch_bounds__(256) void k_tail(
    const unsigned short* __restrict__ h1b, const float* __restrict__ gval,
    const int* __restrict__ gidx, const float* __restrict__ W2,
    const float* __restrict__ b2, const float* __restrict__ W3,
    const float* __restrict__ b3, float* __restrict__ out) {
  __shared__ float W2t[2048], W3t[2048], b2t[128], b3t[256];
  __shared__ float eoL[16][16][17];
  __shared__ float gvL[64][12];
  __shared__ int giL[64][12];
  const int tid = threadIdx.x;
  const int b0 = blockIdx.x * 64;
#pragma unroll
  for (int rep = 0; rep < 8; rep++) {  // coalesced read + LDS transpose
    const int d = rep * 256 + tid;
    W2t[(d & 127) * 16 + (d >> 7)] = W2[d];
    W3t[(d & 127) * 16 + (d >> 7)] = W3[d];
  }
  if (tid < 128) b2t[(tid & 7) * 16 + (tid >> 3)] = b2[tid];
  b3t[(tid & 15) * 16 + (tid >> 4)] = b3[tid];
  if (tid < 192) {
    *(float4*)&((float*)gvL)[tid * 4] = *(const float4*)&gval[(size_t)b0 * 12 + tid * 4];
    *(int4*)&((int*)giL)[tid * 4] = *(const int4*)&gidx[(size_t)b0 * 12 + tid * 4];
  }
  __syncthreads();
  const int e = tid & 15, sr = tid >> 4;
  for (int chunk = 0; chunk < 4; ++chunk) {
    const int row = chunk * 16 + sr;
    const uint4 u0 = *(const uint4*)&h1b[(size_t)(b0 + row) * 256 + e * 16];
    const uint4 u1 = *(const uint4*)&h1b[(size_t)(b0 + row) * 256 + e * 16 + 8];
    float h1v[16];
    {
      const unsigned uu[8] = {u0.x, u0.y, u0.z, u0.w, u1.x, u1.y, u1.z, u1.w};
#pragma unroll
      for (int j = 0; j < 8; j++) {
        h1v[2 * j] = bf2f((unsigned short)(uu[j] & 0xffffu));
        h1v[2 * j + 1] = bf2f((unsigned short)(uu[j] >> 16));
      }
    }
    float h2v[8];
#pragma unroll
    for (int j = 0; j < 8; j++) {
      float a = b2t[j * 16 + e];
#pragma unroll
      for (int k = 0; k < 16; k++) a += h1v[k] * W2t[(k * 8 + j) * 16 + e];
      h2v[j] = fmaxf(a, 0.f);
    }
#pragma unroll
    for (int o = 0; o < 16; o++) {
      float a = b3t[o * 16 + e];
#pragma unroll
      for (int j = 0; j < 8; j++) a += h2v[j] * W3t[(j * 16 + o) * 16 + e];
      eoL[sr][e][o] = fmaxf(a, 0.f);
    }
    __syncthreads();
    {
      const int o = e;
#pragma unroll
      for (int tk = 0; tk < TT; tk++) {
        float y = 0.f;
#pragma unroll
        for (int p = 0; p < 4; p++)
          y += gvL[row][tk * 4 + p] * eoL[sr][giL[row][tk * 4 + p]][o];
        out[((size_t)tk * BSZ + b0 + row) * OO + o] = y;
      }
    }
    __syncthreads();
  }
}

__global__ void k_final(const float* __restrict__ acc_imp,
                        const float* __restrict__ acc_load,
                        const float* __restrict__ rz_acc,
                        float* __restrict__ out_tail) {
  if (threadIdx.x == 0 && blockIdx.x == 0) {
    double lb = 0.0;
    for (int t = 0; t < TT; t++) {
      const float* imp = &acc_imp[t * 16];
      const float* ld = &acc_load[t * 16];
      double si = 0, sl = 0, dot = 0;
      for (int e2 = 0; e2 < 16; e2++) {
        si += imp[e2]; sl += ld[e2]; dot += (double)imp[e2] * ld[e2];
      }
      const double mi = si / 16.0, ml = sl / 16.0;
      double vi = 0, vl = 0;
      for (int e2 = 0; e2 < 16; e2++) {
        const double di = imp[e2] - mi, dl = ld[e2] - ml;
        vi += di * di; vl += dl * dl;
      }
      vi /= 15.0; vl /= 15.0;
      lb += (vi / (mi * mi + 1e-10) + vl / (ml * ml + 1e-10)) * 0.01
          + 16.0 * dot / (double)BSZ * 0.01;
    }
    out_tail[0] = (float)lb;
    out_tail[1] = (float)(3.0 * (rz_acc[0] / (double)BSZ) * 0.001);
  }
}

extern "C" void kernel_launch(void* const* d_in, const int* in_sizes, int n_in,
                              void* d_out, int out_size, void* d_ws, size_t ws_size,
                              hipStream_t stream) {
  const float* x  = (const float*)d_in[0];
  const float* wg = (const float*)d_in[1];
  const float* bg = (const float*)d_in[2];
  const float* W1 = (const float*)d_in[3];
  const float* b1 = (const float*)d_in[4];
  const float* W2 = (const float*)d_in[5];
  const float* b2 = (const float*)d_in[6];
  const float* W3 = (const float*)d_in[7];
  const float* b3 = (const float*)d_in[8];
  float* out = (float*)d_out;

  char* wsb = (char*)d_ws;
  unsigned short* Wth = (unsigned short*)wsb;            //    327,680 B
  unsigned short* h1b = (unsigned short*)(wsb + 327680); // 16,777,216 B
  float* gval = (float*)(wsb + 17104896);                //  1,572,864 B
  int*   gidx = (int*)(wsb + 18677760);                  //  1,572,864 B
  float* acc  = (float*)(wsb + 20250624);                // 97 floats

  k_prepw<<<dim3(160), dim3(256), 0, stream>>>(W1, wg, Wth, acc);
  k_gemm<<<dim3(BSZ / 64), dim3(256), 0, stream>>>(
      x, Wth, b1, bg, wg, h1b, gval, gidx, acc, acc + 48, acc + 96);
  k_tail<<<dim3(BSZ / 64), dim3(256), 0, stream>>>(h1b, gval, gidx, W2, b2, W3, b3,
                                                   out);
  k_final<<<dim3(1), dim3(64), 0, stream>>>(acc, acc + 48, acc + 96,
                                            out + (size_t)TT * BSZ * OO);
}

// Round 5
// 270.806 us; speedup vs baseline: 7.7641x; 1.0924x over previous
//
#include <hip/hip_runtime.h>
#include <hip/hip_bf16.h>

#define BSZ 32768
#define TT  3
#define OO  16

typedef __attribute__((ext_vector_type(8))) short bf16x8;
typedef __attribute__((ext_vector_type(4))) float f32x4;

__device__ __forceinline__ float bf2f(unsigned short u) {
  return __uint_as_float(((unsigned)u) << 16);
}
__device__ __forceinline__ unsigned short f2bf(float f) {
  unsigned u = __float_as_uint(f);
  u += 0x7fffu + ((u >> 16) & 1u);
  return (unsigned short)(u >> 16);
}
__device__ __forceinline__ unsigned pack2(unsigned short a, unsigned short b) {
  return (unsigned)a | ((unsigned)b << 16);
}

// Fragment-major W: Wf[nblk=20][itg=16][lane=64][j=8], element =
// Wt[n = nblk*16 + (lane&15)][k = itg*32 + (lane>>4)*8 + j].
// n<256: W1 cols; 256..303: w_gates; 304..319: zero. Split hi/lo bf16.
__global__ void k_prepw(const float* __restrict__ W1, const float* __restrict__ wg,
                        unsigned short* __restrict__ Wfh,
                        unsigned short* __restrict__ Wfl, float* __restrict__ acc) {
  if (blockIdx.x == 0 && threadIdx.x < 97) acc[threadIdx.x] = 0.f;
  for (int idx = blockIdx.x * 256 + threadIdx.x; idx < 20 * 16 * 64 * 8;
       idx += gridDim.x * 256) {
    const int nblk = idx >> 13, itg = (idx >> 9) & 15;
    const int lane = (idx >> 3) & 63, j = idx & 7;
    const int n = nblk * 16 + (lane & 15);
    const int k = itg * 32 + (lane >> 4) * 8 + j;
    float v = 0.f;
    if (n < 256) v = W1[(size_t)(n >> 4) * 8192 + k * 16 + (n & 15)];
    else if (n < 304) v = wg[(size_t)((n - 256) >> 4) * 8192 + k * 16 + ((n - 256) & 15)];
    const unsigned short hi = f2bf(v);
    Wfh[idx] = hi;
    Wfl[idx] = f2bf(v - bf2f(hi));
  }
}

struct FSmem {
  union {
    struct {                            // phase a: x chunk (BK=128), frag order
      unsigned short xh[4][4][64][8];   // [m][it][lane][8] — 16 KB
      unsigned short xl[4][4][64][8];   // 16 KB
    } a;
    struct {                            // phase b
      unsigned short hd[16][264];       // h1 chunk, bf16
      float eoL[16][16][17];
      float gvL[64][12];
      int   giL[64][12];
      union {
        float lgs[64][52];
        struct { float W2t[2048], W3t[2048]; } t;
      } u2;
      float b2t[128], b3t[256];
      float impL[48], loadL[48];
      int   nresc, resc[192];
      double resL[16];
    } b;
  } u;
  float rzrow[64];
};

__global__ __launch_bounds__(512, 4) void k_fused(
    const float* __restrict__ x, const unsigned short* __restrict__ Wfh,
    const unsigned short* __restrict__ Wfl, const float* __restrict__ b1,
    const float* __restrict__ bg, const float* __restrict__ wg,
    const float* __restrict__ W2, const float* __restrict__ b2,
    const float* __restrict__ W3, const float* __restrict__ b3,
    float* __restrict__ out, float* __restrict__ acc_imp,
    float* __restrict__ acc_load, float* __restrict__ rz_acc) {
  __shared__ FSmem sm;
  const int tid = threadIdx.x;
  const int b0 = blockIdx.x * 64;
  const int w = tid >> 6, l = tid & 63;
  const int l15 = l & 15, quad = l >> 4;
  const int mh = w >> 2;   // row half (0: rows 0-31, 1: rows 32-63)
  const int cg = w & 3;    // col group (80 cols each)
  const int srow = tid >> 3, skf = tid & 7;          // staging: row, float4-slot
  const int sm_abs = srow >> 4;
  const int slane = (srow & 15) + 16 * (skf >> 1);
  const int sj = (skf & 1) * 4;

  f32x4 acc[2][5];
#pragma unroll
  for (int m = 0; m < 2; m++)
#pragma unroll
    for (int c = 0; c < 5; c++) acc[m][c] = (f32x4){0.f, 0.f, 0.f, 0.f};
  float rzsum = 0.f;

  auto woffs = [&](int itg, int c) -> size_t {
    return ((size_t)(((cg * 5 + c) * 16 + itg) * 64 + l)) * 8;
  };

  for (int ch = 0; ch < 4; ++ch) {
    if (ch) __syncthreads();  // protect chunk overwrite
    {
      float4 xv[4];
      const float* xp = &x[(size_t)(b0 + srow) * 512 + ch * 128 + skf * 4];
#pragma unroll
      for (int r = 0; r < 4; r++) xv[r] = *(const float4*)(xp + r * 32);
#pragma unroll
      for (int r = 0; r < 4; r++) {
        const float v0 = xv[r].x, v1 = xv[r].y, v2 = xv[r].z, v3 = xv[r].w;
        rzsum += __expf(v0) + __expf(v1) + __expf(v2) + __expf(v3);
        const unsigned short h0 = f2bf(v0), h1_ = f2bf(v1), h2_ = f2bf(v2), h3 = f2bf(v3);
        uint2 ph, pl;
        ph.x = pack2(h0, h1_); ph.y = pack2(h2_, h3);
        pl.x = pack2(f2bf(v0 - bf2f(h0)), f2bf(v1 - bf2f(h1_)));
        pl.y = pack2(f2bf(v2 - bf2f(h2_)), f2bf(v3 - bf2f(h3)));
        *(uint2*)&sm.u.a.xh[sm_abs][r][slane][sj] = ph;
        *(uint2*)&sm.u.a.xl[sm_abs][r][slane][sj] = pl;
      }
    }
    __syncthreads();

    bf16x8 bh = *(const bf16x8*)&Wfh[woffs(ch * 4, 0)];
    bf16x8 bl = *(const bf16x8*)&Wfl[woffs(ch * 4, 0)];
#pragma unroll
    for (int it = 0; it < 4; ++it) {
      bf16x8 ah[2], al[2];
#pragma unroll
      for (int m = 0; m < 2; m++) {
        ah[m] = *(const bf16x8*)&sm.u.a.xh[mh * 2 + m][it][l][0];
        al[m] = *(const bf16x8*)&sm.u.a.xl[mh * 2 + m][it][l][0];
      }
#pragma unroll
      for (int c = 0; c < 5; c++) {
        bf16x8 bhn = bh, bln = bl;
        if (!((it == 3) && (c == 4))) {  // rolling 1-ahead W prefetch
          const int nit = (c == 4) ? it + 1 : it;
          const int nc  = (c == 4) ? 0 : c + 1;
          const size_t o = woffs(ch * 4 + nit, nc);
          bhn = *(const bf16x8*)&Wfh[o];
          bln = *(const bf16x8*)&Wfl[o];
        }
#pragma unroll
        for (int m = 0; m < 2; m++) {
          acc[m][c] = __builtin_amdgcn_mfma_f32_16x16x32_bf16(ah[m], bh, acc[m][c], 0, 0, 0);
          acc[m][c] = __builtin_amdgcn_mfma_f32_16x16x32_bf16(al[m], bh, acc[m][c], 0, 0, 0);
          acc[m][c] = __builtin_amdgcn_mfma_f32_16x16x32_bf16(ah[m], bl, acc[m][c], 0, 0, 0);
        }
        bh = bhn; bl = bln;
      }
    }
  }

  // ---- router-z: 8 threads share a row ----
  rzsum += __shfl_xor(rzsum, 1);
  rzsum += __shfl_xor(rzsum, 2);
  rzsum += __shfl_xor(rzsum, 4);
  if (skf == 0) sm.rzrow[srow] = rzsum;
  __syncthreads();  // also: MFMA LDS reads done, union reuse safe

  if (tid < 64) {
    float vv = __logf(sm.rzrow[tid]);
#pragma unroll
    for (int off = 32; off; off >>= 1) vv += __shfl_xor(vv, off);
    if (tid == 0) atomicAdd(rz_acc, vv);
  }
  // logits -> lgs (col groups 3 & 7 hold cols 240..319)
  if (cg == 3) {
#pragma unroll
    for (int c = 1; c < 4; c++) {
      const int cc = 16 * c + l15 - 16;  // 0..47
#pragma unroll
      for (int m = 0; m < 2; m++)
#pragma unroll
        for (int reg = 0; reg < 4; reg++) {
          const int row = 32 * mh + 16 * m + quad * 4 + reg;
          sm.u.b.u2.lgs[row][cc] = acc[m][c][reg] + bg[cc];
        }
    }
  }
  if (tid < 48) { sm.u.b.impL[tid] = 0.f; sm.u.b.loadL[tid] = 0.f; }
  if (tid == 0) sm.u.b.nresc = 0;
  __syncthreads();

  // ---- gating: 192 threads = 3 tasks x 64 rows ----
  if (tid < 192) {
    const int r = tid & 63, tk = tid >> 6;
    float v[16];
#pragma unroll
    for (int e = 0; e < 16; e++) v[e] = sm.u.b.u2.lgs[r][tk * 16 + e];
    int idx[5]; float val[5];
#pragma unroll
    for (int p = 0; p < 5; p++) {
      float best = -INFINITY; int bi = 0;
#pragma unroll
      for (int e = 0; e < 16; e++)
        if (v[e] > best) { best = v[e]; bi = e; }
      idx[p] = bi; val[p] = best; v[bi] = -INFINITY;
    }
    if (val[3] - val[4] < 3e-3f) {  // 3-pass logit sigma ~3e-4
      const int s = atomicAdd(&sm.u.b.nresc, 1);
      sm.u.b.resc[s] = (r << 2) | tk;
    }
    const float m = val[0];
    float ex[4], sum = 0.f;
#pragma unroll
    for (int p = 0; p < 4; p++) { ex[p] = __expf(val[p] - m); sum += ex[p]; }
#pragma unroll
    for (int p = 0; p < 4; p++) {
      const float g = ex[p] / sum;
      sm.u.b.gvL[r][tk * 4 + p] = g;
      sm.u.b.giL[r][tk * 4 + p] = idx[p];
      atomicAdd(&sm.u.b.impL[tk * 16 + idx[p]], g);
      atomicAdd(&sm.u.b.loadL[tk * 16 + idx[p]], 1.f);
    }
  }
  __syncthreads();

  // ---- cooperative f64 rescue ----
  const int nr = sm.u.b.nresc;
  for (int i = 0; i < nr; i++) {
    const int st = sm.u.b.resc[i];
    const int r = st >> 2, tk = st & 3;
    if (tid < 256) {
      const int e = tid >> 4, part = tid & 15;
      const float* xr2 = &x[(size_t)(b0 + r) * 512];
      const float* wgc = &wg[(size_t)tk * 8192 + e];
      double a = 0.0;
      for (int d = part * 32; d < part * 32 + 32; d++)
        a += (double)xr2[d] * (double)wgc[(size_t)d * 16];
#pragma unroll
      for (int off = 1; off < 16; off <<= 1) a += __shfl_xor(a, off);
      if (part == 0) sm.u.b.resL[e] = a + (double)bg[tk * 16 + e];
    }
    __syncthreads();
    if (tid == 0) {
      for (int p = 0; p < 4; p++) {
        sm.u.b.impL[tk * 16 + sm.u.b.giL[r][tk * 4 + p]] -= sm.u.b.gvL[r][tk * 4 + p];
        sm.u.b.loadL[tk * 16 + sm.u.b.giL[r][tk * 4 + p]] -= 1.f;
      }
      double vv[16];
      for (int e2 = 0; e2 < 16; e2++) vv[e2] = sm.u.b.resL[e2];
      int idx[4]; float val[4];
      for (int p = 0; p < 4; p++) {
        double best = -1e300; int bi = 0;
        for (int e2 = 0; e2 < 16; e2++)
          if (vv[e2] > best) { best = vv[e2]; bi = e2; }
        idx[p] = bi; val[p] = (float)best; vv[bi] = -1e300;
      }
      const float m = val[0];
      float ex[4], sum = 0.f;
      for (int p = 0; p < 4; p++) { ex[p] = __expf(val[p] - m); sum += ex[p]; }
      for (int p = 0; p < 4; p++) {
        const float g = ex[p] / sum;
        sm.u.b.gvL[r][tk * 4 + p] = g;
        sm.u.b.giL[r][tk * 4 + p] = idx[p];
        sm.u.b.impL[tk * 16 + idx[p]] += g;
        sm.u.b.loadL[tk * 16 + idx[p]] += 1.f;
      }
    }
    __syncthreads();
  }
  if (tid < 48) {
    atomicAdd(&acc_imp[tid], sm.u.b.impL[tid]);
    atomicAdd(&acc_load[tid], sm.u.b.loadL[tid]);
  }

  // ---- tail weights into LDS (overwrites lgs region; gating done) ----
  for (int d = tid; d < 2048; d += 512) {
    sm.u.b.u2.t.W2t[(d & 127) * 16 + (d >> 7)] = W2[d];
    sm.u.b.u2.t.W3t[(d & 127) * 16 + (d >> 7)] = W3[d];
  }
  if (tid < 128) sm.u.b.b2t[(tid & 7) * 16 + (tid >> 3)] = b2[tid];
  if (tid < 256) sm.u.b.b3t[(tid & 15) * 16 + (tid >> 4)] = b3[tid];
  __syncthreads();

  // ---- expert tail + combine, 16-row chunks ----
  for (int ch = 0; ch < 4; ++ch) {
    if (mh == (ch >> 1)) {  // this wave's rows
      const int m = ch & 1;
#pragma unroll
      for (int c = 0; c < 5; c++) {
        const int col = 80 * cg + 16 * c + l15;
        if (col < 256) {
#pragma unroll
          for (int reg = 0; reg < 4; reg++)
            sm.u.b.hd[quad * 4 + reg][col] = f2bf(fmaxf(acc[m][c][reg] + b1[col], 0.f));
        }
      }
    }
    __syncthreads();
    if (tid < 256) {
      const int e = tid & 15, sr = tid >> 4;
      float h1v[16];
#pragma unroll
      for (int q = 0; q < 4; q++) {
        const ushort4 uu = *(const ushort4*)&sm.u.b.hd[sr][e * 16 + q * 4];
        h1v[q * 4 + 0] = bf2f(uu.x);
        h1v[q * 4 + 1] = bf2f(uu.y);
        h1v[q * 4 + 2] = bf2f(uu.z);
        h1v[q * 4 + 3] = bf2f(uu.w);
      }
      float h2v[8];
#pragma unroll
      for (int j = 0; j < 8; j++) {
        float a = sm.u.b.b2t[j * 16 + e];
#pragma unroll
        for (int k = 0; k < 16; k++) a += h1v[k] * sm.u.b.u2.t.W2t[(k * 8 + j) * 16 + e];
        h2v[j] = fmaxf(a, 0.f);
      }
#pragma unroll
      for (int o = 0; o < 16; o++) {
        float a = sm.u.b.b3t[o * 16 + e];
#pragma unroll
        for (int j = 0; j < 8; j++) a += h2v[j] * sm.u.b.u2.t.W3t[(j * 16 + o) * 16 + e];
        sm.u.b.eoL[sr][e][o] = fmaxf(a, 0.f);
      }
    }
    __syncthreads();
    if (tid < 256) {
      const int o = tid & 15, sr = tid >> 4;
      const int rl = ch * 16 + sr;
#pragma unroll
      for (int tk = 0; tk < TT; tk++) {
        float y = 0.f;
#pragma unroll
        for (int p = 0; p < 4; p++)
          y += sm.u.b.gvL[rl][tk * 4 + p] * sm.u.b.eoL[sr][sm.u.b.giL[rl][tk * 4 + p]][o];
        out[((size_t)tk * BSZ + b0 + rl) * OO + o] = y;
      }
    }
    __syncthreads();
  }
}

__global__ void k_final(const float* __restrict__ acc_imp,
                        const float* __restrict__ acc_load,
                        const float* __restrict__ rz_acc,
                        float* __restrict__ out_tail) {
  if (threadIdx.x == 0 && blockIdx.x == 0) {
    double lb = 0.0;
    for (int t = 0; t < TT; t++) {
      const float* imp = &acc_imp[t * 16];
      const float* ld = &acc_load[t * 16];
      double si = 0, sl = 0, dot = 0;
      for (int e2 = 0; e2 < 16; e2++) {
        si += imp[e2]; sl += ld[e2]; dot += (double)imp[e2] * ld[e2];
      }
      const double mi = si / 16.0, ml = sl / 16.0;
      double vi = 0, vl = 0;
      for (int e2 = 0; e2 < 16; e2++) {
        const double di = imp[e2] - mi, dl = ld[e2] - ml;
        vi += di * di; vl += dl * dl;
      }
      vi /= 15.0; vl /= 15.0;
      lb += (vi / (mi * mi + 1e-10) + vl / (ml * ml + 1e-10)) * 0.01
          + 16.0 * dot / (double)BSZ * 0.01;
    }
    out_tail[0] = (float)lb;
    out_tail[1] = (float)(3.0 * (rz_acc[0] / (double)BSZ) * 0.001);
  }
}

extern "C" void kernel_launch(void* const* d_in, const int* in_sizes, int n_in,
                              void* d_out, int out_size, void* d_ws, size_t ws_size,
                              hipStream_t stream) {
  const float* x  = (const float*)d_in[0];
  const float* wg = (const float*)d_in[1];
  const float* bg = (const float*)d_in[2];
  const float* W1 = (const float*)d_in[3];
  const float* b1 = (const float*)d_in[4];
  const float* W2 = (const float*)d_in[5];
  const float* b2 = (const float*)d_in[6];
  const float* W3 = (const float*)d_in[7];
  const float* b3 = (const float*)d_in[8];
  float* out = (float*)d_out;

  char* wsb = (char*)d_ws;
  unsigned short* Wfh = (unsigned short*)wsb;            // 327,680 B
  unsigned short* Wfl = (unsigned short*)(wsb + 327680); // 327,680 B
  float* acc = (float*)(wsb + 655360);                   // 97 floats

  k_prepw<<<dim3(160), dim3(256), 0, stream>>>(W1, wg, Wfh, Wfl, acc);
  k_fused<<<dim3(BSZ / 64), dim3(512), 0, stream>>>(
      x, Wfh, Wfl, b1, bg, wg, W2, b2, W3, b3, out, acc, acc + 48, acc + 96);
  k_final<<<dim3(1), dim3(64), 0, stream>>>(acc, acc + 48, acc + 96,
                                            out + (size_t)TT * BSZ * OO);
}

// Round 6
// 236.789 us; speedup vs baseline: 8.8794x; 1.1437x over previous
//
#include <hip/hip_runtime.h>
#include <hip/hip_bf16.h>

#define BSZ 32768
#define TT  3
#define OO  16

typedef __attribute__((ext_vector_type(8))) short bf16x8;
typedef __attribute__((ext_vector_type(4))) float f32x4;

__device__ __forceinline__ float bf2f(unsigned short u) {
  return __uint_as_float(((unsigned)u) << 16);
}
__device__ __forceinline__ unsigned short f2bf(float f) {
  unsigned u = __float_as_uint(f);
  u += 0x7fffu + ((u >> 16) & 1u);
  return (unsigned short)(u >> 16);
}
__device__ __forceinline__ unsigned pack2(unsigned short a, unsigned short b) {
  return (unsigned)a | ((unsigned)b << 16);
}

// Fragment-major W: Wf[nblk=20][itg=16][lane=64][j=8], element =
// Wt[n = nblk*16 + (lane&15)][k = itg*32 + (lane>>4)*8 + j].
// n<256: W1 cols; 256..303: w_gates; 304..319: zero. Split hi/lo bf16.
__global__ void k_prepw(const float* __restrict__ W1, const float* __restrict__ wg,
                        unsigned short* __restrict__ Wfh,
                        unsigned short* __restrict__ Wfl, float* __restrict__ acc) {
  if (blockIdx.x == 0 && threadIdx.x < 97) acc[threadIdx.x] = 0.f;
  for (int idx = blockIdx.x * 256 + threadIdx.x; idx < 20 * 16 * 64 * 8;
       idx += gridDim.x * 256) {
    const int nblk = idx >> 13, itg = (idx >> 9) & 15;
    const int lane = (idx >> 3) & 63, j = idx & 7;
    const int n = nblk * 16 + (lane & 15);
    const int k = itg * 32 + (lane >> 4) * 8 + j;
    float v = 0.f;
    if (n < 256) v = W1[(size_t)(n >> 4) * 8192 + k * 16 + (n & 15)];
    else if (n < 304) v = wg[(size_t)((n - 256) >> 4) * 8192 + k * 16 + ((n - 256) & 15)];
    const unsigned short hi = f2bf(v);
    Wfh[idx] = hi;
    Wfl[idx] = f2bf(v - bf2f(hi));
  }
}

struct FSmem {
  union {
    struct {                            // phase a: x chunk (BK=128), frag order
      unsigned short xh[4][4][64][8];   // [m][it][lane][8] — 16 KB
      unsigned short xl[4][4][64][8];   // 16 KB
    } a;
    struct {                            // phase b
      unsigned short hd[16][264];       // h1 chunk, bf16
      float eoL[16][16][17];
      float gvL[64][12];
      int   giL[64][12];
      union {
        float lgs[64][52];
        struct { float W2t[2048], W3t[2048]; } t;
      } u2;
      float b2t[128], b3t[256];
      float impL[48], loadL[48];
      int   nresc, resc[192];
      double resL[16];
    } b;
  } u;
  float rzrow[64];
};

__global__ __launch_bounds__(512, 4) void k_fused(
    const float* __restrict__ x, const unsigned short* __restrict__ Wfh,
    const unsigned short* __restrict__ Wfl, const float* __restrict__ b1,
    const float* __restrict__ bg, const float* __restrict__ wg,
    const float* __restrict__ W2, const float* __restrict__ b2,
    const float* __restrict__ W3, const float* __restrict__ b3,
    float* __restrict__ out, float* __restrict__ acc_imp,
    float* __restrict__ acc_load, float* __restrict__ rz_acc) {
  __shared__ FSmem sm;
  const int tid = threadIdx.x;
  const int b0 = blockIdx.x * 64;
  const int w = tid >> 6, l = tid & 63;
  const int l15 = l & 15, quad = l >> 4;
  const int mh = w >> 2;   // row half (0: rows 0-31, 1: rows 32-63)
  const int cg = w & 3;    // col group (80 cols each)
  const int srow = tid >> 3, skf = tid & 7;          // staging: row, float4-slot
  const int sm_abs = srow >> 4;
  const int slane = (srow & 15) + 16 * (skf >> 1);
  const int sj = (skf & 1) * 4;

  f32x4 acc[2][5];
#pragma unroll
  for (int m = 0; m < 2; m++)
#pragma unroll
    for (int c = 0; c < 5; c++) acc[m][c] = (f32x4){0.f, 0.f, 0.f, 0.f};
  float rzsum = 0.f;

  auto woffs = [&](int itg, int c) -> size_t {
    return ((size_t)(((cg * 5 + c) * 16 + itg) * 64 + l)) * 8;
  };

#pragma unroll 1
  for (int ch = 0; ch < 4; ++ch) {
    if (ch) __syncthreads();  // protect chunk overwrite
    {
      float4 xv[4];
      const float* xp = &x[(size_t)(b0 + srow) * 512 + ch * 128 + skf * 4];
#pragma unroll
      for (int r = 0; r < 4; r++) xv[r] = *(const float4*)(xp + r * 32);
#pragma unroll
      for (int r = 0; r < 4; r++) {
        const float v0 = xv[r].x, v1 = xv[r].y, v2 = xv[r].z, v3 = xv[r].w;
        rzsum += __expf(v0) + __expf(v1) + __expf(v2) + __expf(v3);
        const unsigned short h0 = f2bf(v0), h1_ = f2bf(v1), h2_ = f2bf(v2), h3 = f2bf(v3);
        uint2 ph, pl;
        ph.x = pack2(h0, h1_); ph.y = pack2(h2_, h3);
        pl.x = pack2(f2bf(v0 - bf2f(h0)), f2bf(v1 - bf2f(h1_)));
        pl.y = pack2(f2bf(v2 - bf2f(h2_)), f2bf(v3 - bf2f(h3)));
        *(uint2*)&sm.u.a.xh[sm_abs][r][slane][sj] = ph;
        *(uint2*)&sm.u.a.xl[sm_abs][r][slane][sj] = pl;
      }
    }
    __syncthreads();

    bf16x8 bh = *(const bf16x8*)&Wfh[woffs(ch * 4, 0)];
    bf16x8 bl = *(const bf16x8*)&Wfl[woffs(ch * 4, 0)];
#pragma unroll
    for (int it = 0; it < 4; ++it) {
      bf16x8 ah[2], al[2];
#pragma unroll
      for (int m = 0; m < 2; m++) {
        ah[m] = *(const bf16x8*)&sm.u.a.xh[mh * 2 + m][it][l][0];
        al[m] = *(const bf16x8*)&sm.u.a.xl[mh * 2 + m][it][l][0];
      }
#pragma unroll
      for (int c = 0; c < 5; c++) {
        bf16x8 bhn = bh, bln = bl;
        if (!((it == 3) && (c == 4))) {  // rolling 1-ahead W prefetch
          const int nit = (c == 4) ? it + 1 : it;
          const int nc  = (c == 4) ? 0 : c + 1;
          const size_t o = woffs(ch * 4 + nit, nc);
          bhn = *(const bf16x8*)&Wfh[o];
          bln = *(const bf16x8*)&Wfl[o];
        }
#pragma unroll
        for (int m = 0; m < 2; m++) {
          acc[m][c] = __builtin_amdgcn_mfma_f32_16x16x32_bf16(ah[m], bh, acc[m][c], 0, 0, 0);
          acc[m][c] = __builtin_amdgcn_mfma_f32_16x16x32_bf16(al[m], bh, acc[m][c], 0, 0, 0);
          acc[m][c] = __builtin_amdgcn_mfma_f32_16x16x32_bf16(ah[m], bl, acc[m][c], 0, 0, 0);
        }
        bh = bhn; bl = bln;
      }
    }
  }

  // ---- router-z: 8 threads share a row ----
  rzsum += __shfl_xor(rzsum, 1);
  rzsum += __shfl_xor(rzsum, 2);
  rzsum += __shfl_xor(rzsum, 4);
  if (skf == 0) sm.rzrow[srow] = rzsum;
  __syncthreads();  // also: MFMA LDS reads done, union reuse safe

  if (tid < 64) {
    float vv = __logf(sm.rzrow[tid]);
#pragma unroll
    for (int off = 32; off; off >>= 1) vv += __shfl_xor(vv, off);
    if (tid == 0) atomicAdd(rz_acc, vv);
  }
  // logits -> lgs (col group 3 holds cols 240..319)
  if (cg == 3) {
#pragma unroll
    for (int c = 1; c < 4; c++) {
      const int cc = 16 * c + l15 - 16;  // 0..47
#pragma unroll
      for (int m = 0; m < 2; m++)
#pragma unroll
        for (int reg = 0; reg < 4; reg++) {
          const int row = 32 * mh + 16 * m + quad * 4 + reg;
          sm.u.b.u2.lgs[row][cc] = acc[m][c][reg] + bg[cc];
        }
    }
  }
  if (tid < 48) { sm.u.b.impL[tid] = 0.f; sm.u.b.loadL[tid] = 0.f; }
  if (tid == 0) sm.u.b.nresc = 0;
  __syncthreads();

  // ---- gating: 192 threads = 3 tasks x 64 rows (masked top-k, no reg-array writes) ----
  if (tid < 192) {
    const int r = tid & 63, tk = tid >> 6;
    float v[16];
#pragma unroll
    for (int e = 0; e < 16; e++) v[e] = sm.u.b.u2.lgs[r][tk * 16 + e];
    unsigned used = 0;
    int idx[5]; float val[5];
#pragma unroll
    for (int p = 0; p < 5; p++) {
      float best = -INFINITY; int bi = 0;
#pragma unroll
      for (int e = 0; e < 16; e++) {
        const float ve = ((used >> e) & 1u) ? -INFINITY : v[e];
        if (ve > best) { best = ve; bi = e; }
      }
      idx[p] = bi; val[p] = best; used |= 1u << bi;
    }
    if (val[3] - val[4] < 3e-3f) {  // 3-pass logit sigma ~3e-4
      const int s = atomicAdd(&sm.u.b.nresc, 1);
      sm.u.b.resc[s] = (r << 2) | tk;
    }
    const float m = val[0];
    float ex[4], sum = 0.f;
#pragma unroll
    for (int p = 0; p < 4; p++) { ex[p] = __expf(val[p] - m); sum += ex[p]; }
#pragma unroll
    for (int p = 0; p < 4; p++) {
      const float g = ex[p] / sum;
      sm.u.b.gvL[r][tk * 4 + p] = g;
      sm.u.b.giL[r][tk * 4 + p] = idx[p];
      atomicAdd(&sm.u.b.impL[tk * 16 + idx[p]], g);
      atomicAdd(&sm.u.b.loadL[tk * 16 + idx[p]], 1.f);
    }
  }
  __syncthreads();

  // ---- cooperative f64 rescue ----
  const int nr = sm.u.b.nresc;
  for (int i = 0; i < nr; i++) {
    const int st = sm.u.b.resc[i];
    const int r = st >> 2, tk = st & 3;
    if (tid < 256) {
      const int e = tid >> 4, part = tid & 15;
      const float* xr2 = &x[(size_t)(b0 + r) * 512];
      const float* wgc = &wg[(size_t)tk * 8192 + e];
      double a = 0.0;
      for (int d = part * 32; d < part * 32 + 32; d++)
        a += (double)xr2[d] * (double)wgc[(size_t)d * 16];
#pragma unroll
      for (int off = 1; off < 16; off <<= 1) a += __shfl_xor(a, off);
      if (part == 0) sm.u.b.resL[e] = a + (double)bg[tk * 16 + e];
    }
    __syncthreads();
    if (tid == 0) {
      for (int p = 0; p < 4; p++) {
        sm.u.b.impL[tk * 16 + sm.u.b.giL[r][tk * 4 + p]] -= sm.u.b.gvL[r][tk * 4 + p];
        sm.u.b.loadL[tk * 16 + sm.u.b.giL[r][tk * 4 + p]] -= 1.f;
      }
      unsigned used = 0;
      int idx[4]; float val[4];
      for (int p = 0; p < 4; p++) {
        double best = -1e300; int bi = 0;
        for (int e2 = 0; e2 < 16; e2++) {
          if ((used >> e2) & 1u) continue;
          const double ve = sm.u.b.resL[e2];
          if (ve > best) { best = ve; bi = e2; }
        }
        idx[p] = bi; val[p] = (float)best; used |= 1u << bi;
      }
      const float m = val[0];
      float ex[4], sum = 0.f;
      for (int p = 0; p < 4; p++) { ex[p] = __expf(val[p] - m); sum += ex[p]; }
      for (int p = 0; p < 4; p++) {
        const float g = ex[p] / sum;
        sm.u.b.gvL[r][tk * 4 + p] = g;
        sm.u.b.giL[r][tk * 4 + p] = idx[p];
        sm.u.b.impL[tk * 16 + idx[p]] += g;
        sm.u.b.loadL[tk * 16 + idx[p]] += 1.f;
      }
    }
    __syncthreads();
  }
  if (tid < 48) {
    atomicAdd(&acc_imp[tid], sm.u.b.impL[tid]);
    atomicAdd(&acc_load[tid], sm.u.b.loadL[tid]);
  }

  // ---- tail weights into LDS (overwrites lgs region; gating done) ----
  for (int d = tid; d < 2048; d += 512) {
    sm.u.b.u2.t.W2t[(d & 127) * 16 + (d >> 7)] = W2[d];
    sm.u.b.u2.t.W3t[(d & 127) * 16 + (d >> 7)] = W3[d];
  }
  if (tid < 128) sm.u.b.b2t[(tid & 7) * 16 + (tid >> 3)] = b2[tid];
  if (tid < 256) sm.u.b.b3t[(tid & 15) * 16 + (tid >> 4)] = b3[tid];
  __syncthreads();

  // ---- expert tail + combine, 16-row chunks (UNROLLED: acc indices constant) ----
#pragma unroll
  for (int ch = 0; ch < 4; ++ch) {
    if (mh == (ch >> 1)) {  // this wave's rows
      const int m = ch & 1;
#pragma unroll
      for (int c = 0; c < 5; c++) {
        const int col = 80 * cg + 16 * c + l15;
        if (col < 256) {
#pragma unroll
          for (int reg = 0; reg < 4; reg++)
            sm.u.b.hd[quad * 4 + reg][col] = f2bf(fmaxf(acc[m][c][reg] + b1[col], 0.f));
        }
      }
    }
    __syncthreads();
    if (tid < 256) {
      const int e = tid & 15, sr = tid >> 4;
      float h1v[16];
#pragma unroll
      for (int q = 0; q < 4; q++) {
        const ushort4 uu = *(const ushort4*)&sm.u.b.hd[sr][e * 16 + q * 4];
        h1v[q * 4 + 0] = bf2f(uu.x);
        h1v[q * 4 + 1] = bf2f(uu.y);
        h1v[q * 4 + 2] = bf2f(uu.z);
        h1v[q * 4 + 3] = bf2f(uu.w);
      }
      float h2v[8];
#pragma unroll
      for (int j = 0; j < 8; j++) {
        float a = sm.u.b.b2t[j * 16 + e];
#pragma unroll
        for (int k = 0; k < 16; k++) a += h1v[k] * sm.u.b.u2.t.W2t[(k * 8 + j) * 16 + e];
        h2v[j] = fmaxf(a, 0.f);
      }
#pragma unroll
      for (int o = 0; o < 16; o++) {
        float a = sm.u.b.b3t[o * 16 + e];
#pragma unroll
        for (int j = 0; j < 8; j++) a += h2v[j] * sm.u.b.u2.t.W3t[(j * 16 + o) * 16 + e];
        sm.u.b.eoL[sr][e][o] = fmaxf(a, 0.f);
      }
    }
    __syncthreads();
    if (tid < 256) {
      const int o = tid & 15, sr = tid >> 4;
      const int rl = ch * 16 + sr;
#pragma unroll
      for (int tk = 0; tk < TT; tk++) {
        float y = 0.f;
#pragma unroll
        for (int p = 0; p < 4; p++)
          y += sm.u.b.gvL[rl][tk * 4 + p] * sm.u.b.eoL[sr][sm.u.b.giL[rl][tk * 4 + p]][o];
        out[((size_t)tk * BSZ + b0 + rl) * OO + o] = y;
      }
    }
    __syncthreads();
  }
}

__global__ void k_final(const float* __restrict__ acc_imp,
                        const float* __restrict__ acc_load,
                        const float* __restrict__ rz_acc,
                        float* __restrict__ out_tail) {
  if (threadIdx.x == 0 && blockIdx.x == 0) {
    double lb = 0.0;
    for (int t = 0; t < TT; t++) {
      const float* imp = &acc_imp[t * 16];
      const float* ld = &acc_load[t * 16];
      double si = 0, sl = 0, dot = 0;
      for (int e2 = 0; e2 < 16; e2++) {
        si += imp[e2]; sl += ld[e2]; dot += (double)imp[e2] * ld[e2];
      }
      const double mi = si / 16.0, ml = sl / 16.0;
      double vi = 0, vl = 0;
      for (int e2 = 0; e2 < 16; e2++) {
        const double di = imp[e2] - mi, dl = ld[e2] - ml;
        vi += di * di; vl += dl * dl;
      }
      vi /= 15.0; vl /= 15.0;
      lb += (vi / (mi * mi + 1e-10) + vl / (ml * ml + 1e-10)) * 0.01
          + 16.0 * dot / (double)BSZ * 0.01;
    }
    out_tail[0] = (float)lb;
    out_tail[1] = (float)(3.0 * (rz_acc[0] / (double)BSZ) * 0.001);
  }
}

extern "C" void kernel_launch(void* const* d_in, const int* in_sizes, int n_in,
                              void* d_out, int out_size, void* d_ws, size_t ws_size,
                              hipStream_t stream) {
  const float* x  = (const float*)d_in[0];
  const float* wg = (const float*)d_in[1];
  const float* bg = (const float*)d_in[2];
  const float* W1 = (const float*)d_in[3];
  const float* b1 = (const float*)d_in[4];
  const float* W2 = (const float*)d_in[5];
  const float* b2 = (const float*)d_in[6];
  const float* W3 = (const float*)d_in[7];
  const float* b3 = (const float*)d_in[8];
  float* out = (float*)d_out;

  char* wsb = (char*)d_ws;
  unsigned short* Wfh = (unsigned short*)wsb;            // 327,680 B
  unsigned short* Wfl = (unsigned short*)(wsb + 327680); // 327,680 B
  float* acc = (float*)(wsb + 655360);                   // 97 floats

  k_prepw<<<dim3(640), dim3(256), 0, stream>>>(W1, wg, Wfh, Wfl, acc);
  k_fused<<<dim3(BSZ / 64), dim3(512), 0, stream>>>(
      x, Wfh, Wfl, b1, bg, wg, W2, b2, W3, b3, out, acc, acc + 48, acc + 96);
  k_final<<<dim3(1), dim3(64), 0, stream>>>(acc, acc + 48, acc + 96,
                                            out + (size_t)TT * BSZ * OO);
}